// Round 2
// baseline (685.231 us; speedup 1.0000x reference)
//
#include <hip/hip_runtime.h>
#include <hip/hip_bf16.h>

#define N_NODES 50000
#define N_EDGES 1600000
#define NREL    16
#define DIM     64

// Load element i of a float array whose storage dtype is unknown at compile
// time of the HOST but fixed per template instantiation. IS_F32=1: f32
// storage; IS_F32=0: bf16 storage.
template<int IS_F32>
__device__ __forceinline__ float ldx(const void* p, size_t i) {
    if (IS_F32) {
        return ((const float*)p)[i];
    } else {
        unsigned short u = ((const unsigned short*)p)[i];
        return __uint_as_float(((unsigned)u) << 16);
    }
}

// ---------------------------------------------------------------------------
// Dtype detector: read first 1024 words of `norm` as f32. True f32 norm is
// uniform[0,1) -> all finite, small. bf16-packed words read as f32 have
// exponent bits taken from a bf16 exponent/mantissa -> ~2^113 magnitude.
// flag = 1 (f32 dataset) / 0 (bf16 dataset).
// ---------------------------------------------------------------------------
__global__ void k_detect(const float* __restrict__ norm_f, int* __restrict__ flag)
{
    if (blockIdx.x == 0 && threadIdx.x == 0) {
        int ok = 1;
        for (int i = 0; i < 1024; ++i) {
            float v = norm_f[i];
            if (v != v || fabsf(v) > 1e3f) { ok = 0; break; }
        }
        *flag = ok;
    }
}

// Zero the fp32 accumulator (3.2M floats, exactly 3125 blocks x 256 x float4).
__global__ __launch_bounds__(256) void k_zero(float* __restrict__ acc)
{
    int i = blockIdx.x * 256 + threadIdx.x;
    ((float4*)acc)[i] = make_float4(0.f, 0.f, 0.f, 0.f);
}

// ---------------------------------------------------------------------------
// P1-K1: transformed[n][r][o] = sum_d h[n][d] * W[r][d][o]  (bf16 out).
// grid=(391,16), block=256 (4 waves). Wave holds W[r][:,lane] in 64 VGPRs,
// loops 32 nodes with wave-uniform h rows.
// ---------------------------------------------------------------------------
template<int IS_F32>
__global__ __launch_bounds__(256) void k1_transform(
    const void* __restrict__ h_raw,
    const void* __restrict__ w_raw,
    __hip_bfloat16* __restrict__ transformed,
    const int* __restrict__ flag)
{
    if (*flag != IS_F32) return;
    const int r    = blockIdx.y;
    const int lane = threadIdx.x & 63;
    const int wave = threadIdx.x >> 6;

    float wcol[DIM];
    const size_t wbase = (size_t)r * DIM * DIM;
#pragma unroll
    for (int d = 0; d < DIM; ++d)
        wcol[d] = ldx<IS_F32>(w_raw, wbase + d * DIM + lane);

    const int node0 = blockIdx.x * 128 + wave * 32;
    for (int ni = 0; ni < 32; ++ni) {
        int node = __builtin_amdgcn_readfirstlane(node0 + ni);
        if (node >= N_NODES) return;
        const size_t hbase = (size_t)node * DIM;
        float a0 = 0.f, a1 = 0.f, a2 = 0.f, a3 = 0.f;
#pragma unroll
        for (int d = 0; d < DIM; d += 4) {
            a0 = fmaf(ldx<IS_F32>(h_raw, hbase + d + 0), wcol[d + 0], a0);
            a1 = fmaf(ldx<IS_F32>(h_raw, hbase + d + 1), wcol[d + 1], a1);
            a2 = fmaf(ldx<IS_F32>(h_raw, hbase + d + 2), wcol[d + 2], a2);
            a3 = fmaf(ldx<IS_F32>(h_raw, hbase + d + 3), wcol[d + 3], a3);
        }
        float v = (a0 + a1) + (a2 + a3);
        transformed[((size_t)node * NREL + r) * DIM + lane] = __float2bfloat16(v);
    }
}

// ---------------------------------------------------------------------------
// P1-K2: wave per edge: acc[dst*64+o] += transformed[(src*16+rel)*64+o]*norm.
// ---------------------------------------------------------------------------
template<int IS_F32>
__global__ __launch_bounds__(256) void k2_scatter(
    const __hip_bfloat16* __restrict__ transformed,
    const void* __restrict__ norm_raw,
    const int* __restrict__ src,
    const int* __restrict__ dst,
    const int* __restrict__ rel,
    float* __restrict__ acc,
    const int* __restrict__ flag)
{
    if (*flag != IS_F32) return;
    const int lane = threadIdx.x & 63;
    int gw = blockIdx.x * 4 + (threadIdx.x >> 6);
    int nw = gridDim.x * 4;

    for (int e = gw; e < N_EDGES; e += nw) {
        int   s  = src[e];
        int   dv = dst[e];
        int   rv = rel[e];
        float nv = ldx<IS_F32>(norm_raw, e);
        float t  = __bfloat162float(transformed[((size_t)s * NREL + rv) * DIM + lane]);
        unsafeAtomicAdd(&acc[(size_t)dv * DIM + lane], t * nv);
    }
}

// ---------------------------------------------------------------------------
// P2 (small-ws fallback): per-edge direct matvec, W cached in LDS 4 rels at a
// time (32 KB), 4 passes over the edge list.
// ---------------------------------------------------------------------------
template<int IS_F32>
__global__ __launch_bounds__(256) void k2_direct(
    const void* __restrict__ h_raw,
    const void* __restrict__ w_raw,
    const void* __restrict__ norm_raw,
    const int* __restrict__ src,
    const int* __restrict__ dst,
    const int* __restrict__ rel,
    float* __restrict__ acc,
    const int* __restrict__ flag,
    int rel_lo)
{
    if (*flag != IS_F32) return;
    __shared__ __hip_bfloat16 Wl[4 * DIM * DIM];   // 32 KB
    for (int i = threadIdx.x; i < 4 * DIM * DIM; i += 256)
        Wl[i] = __float2bfloat16(ldx<IS_F32>(w_raw, (size_t)rel_lo * DIM * DIM + i));
    __syncthreads();

    const int lane = threadIdx.x & 63;
    int gw = blockIdx.x * 4 + (threadIdx.x >> 6);
    int nw = gridDim.x * 4;

    for (int e = gw; e < N_EDGES; e += nw) {
        int rv = rel[e];
        if ((unsigned)(rv - rel_lo) >= 4u) continue;
        int   s  = src[e];
        int   dv = dst[e];
        float nv = ldx<IS_F32>(norm_raw, e);
        const size_t hbase = (size_t)s * DIM;
        const int    wb    = (rv - rel_lo) * DIM * DIM;
        float a0 = 0.f, a1 = 0.f;
#pragma unroll
        for (int d = 0; d < DIM; d += 2) {
            a0 = fmaf(ldx<IS_F32>(h_raw, hbase + d + 0),
                      __bfloat162float(Wl[wb + (d + 0) * DIM + lane]), a0);
            a1 = fmaf(ldx<IS_F32>(h_raw, hbase + d + 1),
                      __bfloat162float(Wl[wb + (d + 1) * DIM + lane]), a1);
        }
        unsafeAtomicAdd(&acc[(size_t)dv * DIM + lane], (a0 + a1) * nv);
    }
}

// ---------------------------------------------------------------------------
// K3: out = dtype(relu(acc)). 4 elems/thread, 3125 blocks x 256.
// ---------------------------------------------------------------------------
template<int IS_F32>
__global__ __launch_bounds__(256) void k3_relu(
    const float* __restrict__ acc,
    void* __restrict__ out,
    const int* __restrict__ flag)
{
    if (*flag != IS_F32) return;
    int i = blockIdx.x * 256 + threadIdx.x;
    int base = i * 4;
    float4 v = *(const float4*)(acc + base);
    float r0 = fmaxf(v.x, 0.f), r1 = fmaxf(v.y, 0.f);
    float r2 = fmaxf(v.z, 0.f), r3 = fmaxf(v.w, 0.f);
    if (IS_F32) {
        ((float4*)out)[i] = make_float4(r0, r1, r2, r3);
    } else {
        __hip_bfloat16 b0 = __float2bfloat16(r0);
        __hip_bfloat16 b1 = __float2bfloat16(r1);
        __hip_bfloat16 b2 = __float2bfloat16(r2);
        __hip_bfloat16 b3 = __float2bfloat16(r3);
        unsigned short us[4];
        __builtin_memcpy(&us[0], &b0, 2);
        __builtin_memcpy(&us[1], &b1, 2);
        __builtin_memcpy(&us[2], &b2, 2);
        __builtin_memcpy(&us[3], &b3, 2);
        ushort4 pk; pk.x = us[0]; pk.y = us[1]; pk.z = us[2]; pk.w = us[3];
        ((ushort4*)out)[i] = pk;
    }
}

// ---------------------------------------------------------------------------
extern "C" void kernel_launch(void* const* d_in, const int* in_sizes, int n_in,
                              void* d_out, int out_size, void* d_ws, size_t ws_size,
                              hipStream_t stream)
{
    const void* h      = d_in[0];
    const void* weight = d_in[1];
    const void* norm   = d_in[2];
    const int* src = (const int*)d_in[3];
    const int* dst = (const int*)d_in[4];
    const int* rel = (const int*)d_in[5];

    // ws layout: [0,256): int flag | acc f32 [3.2M] | transformed bf16 [51.2M]
    int*   flag = (int*)d_ws;
    float* acc  = (float*)((char*)d_ws + 256);
    __hip_bfloat16* transformed =
        (__hip_bfloat16*)((char*)d_ws + 256 + (size_t)N_NODES * DIM * 4);

    const size_t NEED_P1 = 256 + (size_t)N_NODES * DIM * 4
                               + (size_t)N_NODES * NREL * DIM * 2;

    k_detect<<<1, 64, 0, stream>>>((const float*)norm, flag);
    k_zero<<<3125, 256, 0, stream>>>(acc);

    if (ws_size >= NEED_P1) {
        dim3 g1((N_NODES + 127) / 128, NREL);
        k1_transform<0><<<g1, 256, 0, stream>>>(h, weight, transformed, flag);
        k1_transform<1><<<g1, 256, 0, stream>>>(h, weight, transformed, flag);
        k2_scatter<0><<<4096, 256, 0, stream>>>(transformed, norm, src, dst, rel, acc, flag);
        k2_scatter<1><<<4096, 256, 0, stream>>>(transformed, norm, src, dst, rel, acc, flag);
    } else {
        for (int r0 = 0; r0 < NREL; r0 += 4) {
            k2_direct<0><<<2048, 256, 0, stream>>>(h, weight, norm, src, dst, rel, acc, flag, r0);
            k2_direct<1><<<2048, 256, 0, stream>>>(h, weight, norm, src, dst, rel, acc, flag, r0);
        }
    }

    k3_relu<0><<<3125, 256, 0, stream>>>(acc, d_out, flag);
    k3_relu<1><<<3125, 256, 0, stream>>>(acc, d_out, flag);
}

// Round 3
// 621.500 us; speedup vs baseline: 1.1025x; 1.1025x over previous
//
#include <hip/hip_runtime.h>
#include <hip/hip_bf16.h>

#define N_NODES 50000
#define N_EDGES 1600000
#define NREL    16
#define DIM     64

template<int IS_F32>
__device__ __forceinline__ float ldx(const void* p, size_t i) {
    if (IS_F32) {
        return ((const float*)p)[i];
    } else {
        unsigned short u = ((const unsigned short*)p)[i];
        return __uint_as_float(((unsigned)u) << 16);
    }
}

__device__ __forceinline__ float bfbits2f(unsigned short u) {
    return __uint_as_float(((unsigned)u) << 16);
}

// ---------------------------------------------------------------------------
// Dtype detector (unchanged, proven): flag=1 if arrays are f32, 0 if bf16.
// ---------------------------------------------------------------------------
__global__ void k_detect(const float* __restrict__ norm_f, int* __restrict__ flag)
{
    if (blockIdx.x == 0 && threadIdx.x == 0) {
        int ok = 1;
        for (int i = 0; i < 1024; ++i) {
            float v = norm_f[i];
            if (v != v || fabsf(v) > 1e3f) { ok = 0; break; }
        }
        *flag = ok;
    }
}

// ---------------------------------------------------------------------------
// CSR build: zero counts -> histogram(dst) -> exclusive scan -> fill sorted.
// ---------------------------------------------------------------------------
__global__ __launch_bounds__(256) void k_zero_counts(int* __restrict__ counts)
{
    int i = blockIdx.x * 256 + threadIdx.x;
    if (i < N_NODES) counts[i] = 0;
}

__global__ __launch_bounds__(256) void k_hist(
    const int* __restrict__ dst, int* __restrict__ counts)
{
    int e = blockIdx.x * 256 + threadIdx.x;
    if (e < N_EDGES) atomicAdd(&counts[dst[e]], 1);
}

// Single-block exclusive scan of counts[50000] -> A (read-only starts) and
// B (mutable cursors, becomes ends after k_fill). 1024 threads, shfl+LDS.
__global__ __launch_bounds__(1024) void k_scan(
    const int* __restrict__ counts, int* __restrict__ A, int* __restrict__ B)
{
    __shared__ int lds[17];
    const int tid = threadIdx.x, lane = tid & 63, wid = tid >> 6;
    int carry = 0;
    const int nchunk = (N_NODES + 1023) / 1024;
    for (int chunk = 0; chunk < nchunk; ++chunk) {
        int i = chunk * 1024 + tid;
        int c = (i < N_NODES) ? counts[i] : 0;
        int incl = c;
#pragma unroll
        for (int off = 1; off < 64; off <<= 1) {
            int t = __shfl_up(incl, off, 64);
            if (lane >= off) incl += t;
        }
        if (lane == 63) lds[wid] = incl;
        __syncthreads();
        if (wid == 0 && lane < 16) {
            int s = lds[lane];
            int si = s;
#pragma unroll
            for (int off = 1; off < 16; off <<= 1) {
                int t = __shfl_up(si, off, 64);
                if (lane >= off) si += t;
            }
            lds[lane] = si - s;            // exclusive wave offset
            if (lane == 15) lds[16] = si;  // chunk total
        }
        __syncthreads();
        int excl = carry + lds[wid] + (incl - c);
        if (i < N_NODES) { A[i] = excl; B[i] = excl; }
        carry += lds[16];
        __syncthreads();                   // lds reused next chunk
    }
}

template<int IS_F32>
__global__ __launch_bounds__(256) void k_fill(
    const int* __restrict__ src, const int* __restrict__ dst,
    const int* __restrict__ rel, const void* __restrict__ norm_raw,
    int* __restrict__ B, unsigned* __restrict__ packed,
    unsigned short* __restrict__ normS, const int* __restrict__ flag)
{
    if (*flag != IS_F32) return;
    int e = blockIdx.x * 256 + threadIdx.x;
    if (e >= N_EDGES) return;
    int d = dst[e];
    int pos = atomicAdd(&B[d], 1);
    packed[pos] = (unsigned)src[e] | ((unsigned)rel[e] << 16);
    float nv = ldx<IS_F32>(norm_raw, e);
    __hip_bfloat16 nb = __float2bfloat16(nv);
    unsigned short us; __builtin_memcpy(&us, &nb, 2);
    normS[pos] = us;
}

// ---------------------------------------------------------------------------
// K1: transformed[n][r][o] = sum_d h[n][d] * W[r][d][o]  (bf16 out). Unchanged.
// ---------------------------------------------------------------------------
template<int IS_F32>
__global__ __launch_bounds__(256) void k1_transform(
    const void* __restrict__ h_raw,
    const void* __restrict__ w_raw,
    __hip_bfloat16* __restrict__ transformed,
    const int* __restrict__ flag)
{
    if (*flag != IS_F32) return;
    const int r    = blockIdx.y;
    const int lane = threadIdx.x & 63;
    const int wave = threadIdx.x >> 6;

    float wcol[DIM];
    const size_t wbase = (size_t)r * DIM * DIM;
#pragma unroll
    for (int d = 0; d < DIM; ++d)
        wcol[d] = ldx<IS_F32>(w_raw, wbase + d * DIM + lane);

    const int node0 = blockIdx.x * 128 + wave * 32;
    for (int ni = 0; ni < 32; ++ni) {
        int node = __builtin_amdgcn_readfirstlane(node0 + ni);
        if (node >= N_NODES) return;
        const size_t hbase = (size_t)node * DIM;
        float a0 = 0.f, a1 = 0.f, a2 = 0.f, a3 = 0.f;
#pragma unroll
        for (int d = 0; d < DIM; d += 4) {
            a0 = fmaf(ldx<IS_F32>(h_raw, hbase + d + 0), wcol[d + 0], a0);
            a1 = fmaf(ldx<IS_F32>(h_raw, hbase + d + 1), wcol[d + 1], a1);
            a2 = fmaf(ldx<IS_F32>(h_raw, hbase + d + 2), wcol[d + 2], a2);
            a3 = fmaf(ldx<IS_F32>(h_raw, hbase + d + 3), wcol[d + 3], a3);
        }
        float v = (a0 + a1) + (a2 + a3);
        transformed[((size_t)node * NREL + r) * DIM + lane] = __float2bfloat16(v);
    }
}

// ---------------------------------------------------------------------------
// K_ACC: one wave per dst node; accumulate its CSR edge range, fused relu +
// store. No atomics. start=A[v], end=B[v] (post-fill cursor).
// ---------------------------------------------------------------------------
template<int IS_F32>
__global__ __launch_bounds__(256) void k_acc(
    const unsigned* __restrict__ packed,
    const unsigned short* __restrict__ normS,
    const __hip_bfloat16* __restrict__ transformed,
    const int* __restrict__ A, const int* __restrict__ B,
    void* __restrict__ out, const int* __restrict__ flag)
{
    if (*flag != IS_F32) return;
    const int lane = threadIdx.x & 63;
    const int v = blockIdx.x * 4 + (threadIdx.x >> 6);
    if (v >= N_NODES) return;

    const int start = __builtin_amdgcn_readfirstlane(A[v]);
    const int end   = __builtin_amdgcn_readfirstlane(B[v]);

    const unsigned short* tb = (const unsigned short*)transformed;
    float a = 0.f;
    int i = start;
    for (; i + 2 <= end; i += 2) {
        unsigned u0 = packed[i], u1 = packed[i + 1];
        float n0 = bfbits2f(normS[i]), n1 = bfbits2f(normS[i + 1]);
        unsigned off0 = ((u0 & 0xFFFFu) * NREL + (u0 >> 16)) * DIM + lane;
        unsigned off1 = ((u1 & 0xFFFFu) * NREL + (u1 >> 16)) * DIM + lane;
        float t0 = bfbits2f(tb[off0]);
        float t1 = bfbits2f(tb[off1]);
        a = fmaf(t0, n0, a);
        a = fmaf(t1, n1, a);
    }
    if (i < end) {
        unsigned u0 = packed[i];
        float n0 = bfbits2f(normS[i]);
        unsigned off0 = ((u0 & 0xFFFFu) * NREL + (u0 >> 16)) * DIM + lane;
        a = fmaf(bfbits2f(tb[off0]), n0, a);
    }

    float r = fmaxf(a, 0.f);
    const size_t ob = (size_t)v * DIM + lane;
    if (IS_F32) {
        ((float*)out)[ob] = r;
    } else {
        __hip_bfloat16 b = __float2bfloat16(r);
        unsigned short us; __builtin_memcpy(&us, &b, 2);
        ((unsigned short*)out)[ob] = us;
    }
}

// ---------------------------------------------------------------------------
extern "C" void kernel_launch(void* const* d_in, const int* in_sizes, int n_in,
                              void* d_out, int out_size, void* d_ws, size_t ws_size,
                              hipStream_t stream)
{
    const void* h      = d_in[0];
    const void* weight = d_in[1];
    const void* norm   = d_in[2];
    const int* src = (const int*)d_in[3];
    const int* dst = (const int*)d_in[4];
    const int* rel = (const int*)d_in[5];

    // ws layout (256-B aligned chunks):
    //  flag(256) | A[50001] | B[50001] | counts[50000] | packed u32[E]
    //  | normS u16[E] | transformed bf16[N*R*64]
    char* w = (char*)d_ws;
    int*   flag   = (int*)w;                 w += 256;
    int*   A      = (int*)w;                 w += 200192;
    int*   B      = (int*)w;                 w += 200192;
    int*   counts = (int*)w;                 w += 200192;
    unsigned* packed = (unsigned*)w;         w += (size_t)N_EDGES * 4;
    unsigned short* normS = (unsigned short*)w; w += (size_t)N_EDGES * 2;
    __hip_bfloat16* transformed = (__hip_bfloat16*)w;

    k_detect<<<1, 64, 0, stream>>>((const float*)norm, flag);

    // CSR build
    k_zero_counts<<<196, 256, 0, stream>>>(counts);
    k_hist<<<6250, 256, 0, stream>>>(dst, counts);
    k_scan<<<1, 1024, 0, stream>>>(counts, A, B);
    k_fill<0><<<6250, 256, 0, stream>>>(src, dst, rel, norm, B, packed, normS, flag);
    k_fill<1><<<6250, 256, 0, stream>>>(src, dst, rel, norm, B, packed, normS, flag);

    // transform
    dim3 g1((N_NODES + 127) / 128, NREL);
    k1_transform<0><<<g1, 256, 0, stream>>>(h, weight, transformed, flag);
    k1_transform<1><<<g1, 256, 0, stream>>>(h, weight, transformed, flag);

    // accumulate + relu
    k_acc<0><<<12500, 256, 0, stream>>>(packed, normS, transformed, A, B, d_out, flag);
    k_acc<1><<<12500, 256, 0, stream>>>(packed, normS, transformed, A, B, d_out, flag);
}

// Round 4
// 499.250 us; speedup vs baseline: 1.3725x; 1.2449x over previous
//
#include <hip/hip_runtime.h>
#include <hip/hip_bf16.h>

#define N_NODES 50000
#define N_EDGES 1600000
#define NREL    16
#define DIM     64

typedef __attribute__((ext_vector_type(8))) short short8;
typedef __attribute__((ext_vector_type(4))) float float4v;

template<int IS_F32>
__device__ __forceinline__ float ldx(const void* p, size_t i) {
    if (IS_F32) {
        return ((const float*)p)[i];
    } else {
        unsigned short u = ((const unsigned short*)p)[i];
        return __uint_as_float(((unsigned)u) << 16);
    }
}

__device__ __forceinline__ float bfbits2f(unsigned short u) {
    return __uint_as_float(((unsigned)u) << 16);
}

__device__ __forceinline__ unsigned short f2bfbits(float v) {
    __hip_bfloat16 b = __float2bfloat16(v);
    unsigned short us; __builtin_memcpy(&us, &b, 2);
    return us;
}

// ---------------------------------------------------------------------------
// Dtype detector (proven): flag=1 if arrays are f32, 0 if bf16.
// ---------------------------------------------------------------------------
__global__ void k_detect(const float* __restrict__ norm_f, int* __restrict__ flag)
{
    if (blockIdx.x == 0 && threadIdx.x == 0) {
        int ok = 1;
        for (int i = 0; i < 1024; ++i) {
            float v = norm_f[i];
            if (v != v || fabsf(v) > 1e3f) { ok = 0; break; }
        }
        *flag = ok;
    }
}

// ---------------------------------------------------------------------------
// CSR build (proven): zero -> histogram(dst) -> scan -> fill sorted arrays.
// ---------------------------------------------------------------------------
__global__ __launch_bounds__(256) void k_zero_counts(int* __restrict__ counts)
{
    int i = blockIdx.x * 256 + threadIdx.x;
    if (i < N_NODES) counts[i] = 0;
}

__global__ __launch_bounds__(256) void k_hist(
    const int* __restrict__ dst, int* __restrict__ counts)
{
    int e = blockIdx.x * 256 + threadIdx.x;
    if (e < N_EDGES) atomicAdd(&counts[dst[e]], 1);
}

__global__ __launch_bounds__(1024) void k_scan(
    const int* __restrict__ counts, int* __restrict__ A, int* __restrict__ B)
{
    __shared__ int lds[17];
    const int tid = threadIdx.x, lane = tid & 63, wid = tid >> 6;
    int carry = 0;
    const int nchunk = (N_NODES + 1023) / 1024;
    for (int chunk = 0; chunk < nchunk; ++chunk) {
        int i = chunk * 1024 + tid;
        int c = (i < N_NODES) ? counts[i] : 0;
        int incl = c;
#pragma unroll
        for (int off = 1; off < 64; off <<= 1) {
            int t = __shfl_up(incl, off, 64);
            if (lane >= off) incl += t;
        }
        if (lane == 63) lds[wid] = incl;
        __syncthreads();
        if (wid == 0 && lane < 16) {
            int s = lds[lane];
            int si = s;
#pragma unroll
            for (int off = 1; off < 16; off <<= 1) {
                int t = __shfl_up(si, off, 64);
                if (lane >= off) si += t;
            }
            lds[lane] = si - s;
            if (lane == 15) lds[16] = si;
        }
        __syncthreads();
        int excl = carry + lds[wid] + (incl - c);
        if (i < N_NODES) { A[i] = excl; B[i] = excl; }
        carry += lds[16];
        __syncthreads();
    }
}

template<int IS_F32>
__global__ __launch_bounds__(256) void k_fill(
    const int* __restrict__ src, const int* __restrict__ dst,
    const int* __restrict__ rel, const void* __restrict__ norm_raw,
    int* __restrict__ B, unsigned* __restrict__ packed,
    unsigned short* __restrict__ normS, const int* __restrict__ flag)
{
    if (*flag != IS_F32) return;
    int e = blockIdx.x * 256 + threadIdx.x;
    if (e >= N_EDGES) return;
    int d = dst[e];
    int pos = atomicAdd(&B[d], 1);
    packed[pos] = (unsigned)src[e] | ((unsigned)rel[e] << 16);
    normS[pos] = f2bfbits(ldx<IS_F32>(norm_raw, e));
}

// ---------------------------------------------------------------------------
// K1 (MFMA): transformed[n][r][o] = sum_d h[n][d]*W[r][d][o], bf16 out.
// grid=(782 node-tiles, 4 rel-groups), block=256 (4 waves, 16 nodes/wave).
// MFMA 16x16x32 bf16.  A[m=lane&15][k=quad*8+j]  (m120-verified),
// B[k=quad*8+j][n=lane&15], D: row m=quad*4+reg, col n=lane&15 (m89-verified).
// W slice swizzled to LDS in B-frag order; stride 40 shorts per n keeps
// ds_read_b128 16-B aligned and spreads banks.
// ---------------------------------------------------------------------------
template<int IS_F32>
__device__ __forceinline__ short8 load_afrag(const void* h_raw, int row, int quad, int half)
{
    short8 r;
    if (IS_F32) {
        const float4* p = (const float4*)((const char*)h_raw + (size_t)row * 256 + half * 128 + quad * 32);
        float4 f0 = p[0], f1 = p[1];
        float fv[8] = {f0.x, f0.y, f0.z, f0.w, f1.x, f1.y, f1.z, f1.w};
#pragma unroll
        for (int j = 0; j < 8; ++j) r[j] = (short)f2bfbits(fv[j]);
    } else {
        uint4 v = *(const uint4*)((const char*)h_raw + (size_t)row * 128 + half * 64 + quad * 16);
        __builtin_memcpy(&r, &v, 16);
    }
    return r;
}

template<int IS_F32>
__global__ __launch_bounds__(256) void k1_mfma(
    const void* __restrict__ h_raw,
    const void* __restrict__ w_raw,
    __hip_bfloat16* __restrict__ transformed,
    const int* __restrict__ flag)
{
    if (*flag != IS_F32) return;
    const int lane = threadIdx.x & 63;
    const int wave = threadIdx.x >> 6;
    const int n15  = lane & 15;
    const int quad = lane >> 4;
    const int rbase = blockIdx.y * 4;

    // Wl[((rl*2+c)*64 + n)*40 + quad*8 + j] = W[rbase+rl][c*32+quad*8+j][n]
    __shared__ short Wl[4 * 2 * 64 * 40];   // 40 KB

    for (int idx = threadIdx.x; idx < 4 * 64 * 64; idx += 256) {
        int o = idx & 63, d = (idx >> 6) & 63, rl = idx >> 12;
        float wv = ldx<IS_F32>(w_raw, (size_t)((rbase + rl) * 64 + d) * 64 + o);
        int c = d >> 5, q = (d >> 3) & 3, j = d & 7;
        Wl[((rl * 2 + c) * 64 + o) * 40 + q * 8 + j] = (short)f2bfbits(wv);
    }
    __syncthreads();

    const int node0 = blockIdx.x * 64 + wave * 16;
    if (node0 >= N_NODES) return;   // 50000 % 16 == 0: wave fully in or out

    short8 a0 = load_afrag<IS_F32>(h_raw, node0 + n15, quad, 0);
    short8 a1 = load_afrag<IS_F32>(h_raw, node0 + n15, quad, 1);

    unsigned short* tb = (unsigned short*)transformed;

#pragma unroll
    for (int rl = 0; rl < 4; ++rl) {
        float4v acc[4];
#pragma unroll
        for (int t = 0; t < 4; ++t) acc[t] = (float4v){0.f, 0.f, 0.f, 0.f};

#pragma unroll
        for (int t = 0; t < 4; ++t) {
            const short8* b0 = (const short8*)&Wl[((rl * 2 + 0) * 64 + t * 16 + n15) * 40 + quad * 8];
            acc[t] = __builtin_amdgcn_mfma_f32_16x16x32_bf16(a0, *b0, acc[t], 0, 0, 0);
        }
#pragma unroll
        for (int t = 0; t < 4; ++t) {
            const short8* b1 = (const short8*)&Wl[((rl * 2 + 1) * 64 + t * 16 + n15) * 40 + quad * 8];
            acc[t] = __builtin_amdgcn_mfma_f32_16x16x32_bf16(a1, *b1, acc[t], 0, 0, 0);
        }

        const int r = rbase + rl;
#pragma unroll
        for (int t = 0; t < 4; ++t) {
#pragma unroll
            for (int i = 0; i < 4; ++i) {
                int node = node0 + quad * 4 + i;
                tb[((size_t)node * NREL + r) * DIM + t * 16 + n15] = f2bfbits(acc[t][i]);
            }
        }
    }
}

// ---------------------------------------------------------------------------
// K_ACC (proven): one wave per dst node; accumulate CSR range, relu, store.
// ---------------------------------------------------------------------------
template<int IS_F32>
__global__ __launch_bounds__(256) void k_acc(
    const unsigned* __restrict__ packed,
    const unsigned short* __restrict__ normS,
    const __hip_bfloat16* __restrict__ transformed,
    const int* __restrict__ A, const int* __restrict__ B,
    void* __restrict__ out, const int* __restrict__ flag)
{
    if (*flag != IS_F32) return;
    const int lane = threadIdx.x & 63;
    const int v = blockIdx.x * 4 + (threadIdx.x >> 6);
    if (v >= N_NODES) return;

    const int start = __builtin_amdgcn_readfirstlane(A[v]);
    const int end   = __builtin_amdgcn_readfirstlane(B[v]);

    const unsigned short* tb = (const unsigned short*)transformed;
    float a = 0.f;
    int i = start;
    for (; i + 2 <= end; i += 2) {
        unsigned u0 = packed[i], u1 = packed[i + 1];
        float n0 = bfbits2f(normS[i]), n1 = bfbits2f(normS[i + 1]);
        unsigned off0 = ((u0 & 0xFFFFu) * NREL + (u0 >> 16)) * DIM + lane;
        unsigned off1 = ((u1 & 0xFFFFu) * NREL + (u1 >> 16)) * DIM + lane;
        float t0 = bfbits2f(tb[off0]);
        float t1 = bfbits2f(tb[off1]);
        a = fmaf(t0, n0, a);
        a = fmaf(t1, n1, a);
    }
    if (i < end) {
        unsigned u0 = packed[i];
        float n0 = bfbits2f(normS[i]);
        unsigned off0 = ((u0 & 0xFFFFu) * NREL + (u0 >> 16)) * DIM + lane;
        a = fmaf(bfbits2f(tb[off0]), n0, a);
    }

    float r = fmaxf(a, 0.f);
    const size_t ob = (size_t)v * DIM + lane;
    if (IS_F32) {
        ((float*)out)[ob] = r;
    } else {
        ((unsigned short*)out)[ob] = f2bfbits(r);
    }
}

// ---------------------------------------------------------------------------
extern "C" void kernel_launch(void* const* d_in, const int* in_sizes, int n_in,
                              void* d_out, int out_size, void* d_ws, size_t ws_size,
                              hipStream_t stream)
{
    const void* h      = d_in[0];
    const void* weight = d_in[1];
    const void* norm   = d_in[2];
    const int* src = (const int*)d_in[3];
    const int* dst = (const int*)d_in[4];
    const int* rel = (const int*)d_in[5];

    char* w = (char*)d_ws;
    int*   flag   = (int*)w;                    w += 256;
    int*   A      = (int*)w;                    w += 200192;
    int*   B      = (int*)w;                    w += 200192;
    int*   counts = (int*)w;                    w += 200192;
    unsigned* packed = (unsigned*)w;            w += (size_t)N_EDGES * 4;
    unsigned short* normS = (unsigned short*)w; w += (size_t)N_EDGES * 2;
    __hip_bfloat16* transformed = (__hip_bfloat16*)w;

    k_detect<<<1, 64, 0, stream>>>((const float*)norm, flag);

    k_zero_counts<<<196, 256, 0, stream>>>(counts);
    k_hist<<<6250, 256, 0, stream>>>(dst, counts);
    k_scan<<<1, 1024, 0, stream>>>(counts, A, B);
    k_fill<0><<<6250, 256, 0, stream>>>(src, dst, rel, norm, B, packed, normS, flag);
    k_fill<1><<<6250, 256, 0, stream>>>(src, dst, rel, norm, B, packed, normS, flag);

    dim3 g1((N_NODES + 63) / 64, 4);
    k1_mfma<0><<<g1, 256, 0, stream>>>(h, weight, transformed, flag);
    k1_mfma<1><<<g1, 256, 0, stream>>>(h, weight, transformed, flag);

    k_acc<0><<<12500, 256, 0, stream>>>(packed, normS, transformed, A, B, d_out, flag);
    k_acc<1><<<12500, 256, 0, stream>>>(packed, normS, transformed, A, B, d_out, flag);
}

// Round 5
// 449.955 us; speedup vs baseline: 1.5229x; 1.1096x over previous
//
#include <hip/hip_runtime.h>
#include <hip/hip_bf16.h>

#define N_NODES 50000
#define N_EDGES 1600000
#define NREL    16
#define DIM     64

#define NBKT    391           // ceil(50000/128) buckets of 128 dst nodes
#define P1_CHUNK 2048
#define P1_GRID  782          // ceil(1.6M/2048)

typedef __attribute__((ext_vector_type(8))) short short8;
typedef __attribute__((ext_vector_type(4))) float float4v;

template<int IS_F32>
__device__ __forceinline__ float ldx(const void* p, size_t i) {
    if (IS_F32) {
        return ((const float*)p)[i];
    } else {
        unsigned short u = ((const unsigned short*)p)[i];
        return __uint_as_float(((unsigned)u) << 16);
    }
}

__device__ __forceinline__ float bfbits2f(unsigned short u) {
    return __uint_as_float(((unsigned)u) << 16);
}

__device__ __forceinline__ unsigned short f2bfbits(float v) {
    __hip_bfloat16 b = __float2bfloat16(v);
    unsigned short us; __builtin_memcpy(&us, &b, 2);
    return us;
}

// ---------------------------------------------------------------------------
// Dtype detector (proven): flag=1 if arrays are f32, 0 if bf16.
// ---------------------------------------------------------------------------
__global__ void k_detect(const float* __restrict__ norm_f, int* __restrict__ flag)
{
    if (blockIdx.x == 0 && threadIdx.x == 0) {
        int ok = 1;
        for (int i = 0; i < 1024; ++i) {
            float v = norm_f[i];
            if (v != v || fabsf(v) > 1e3f) { ok = 0; break; }
        }
        *flag = ok;
    }
}

// ---------------------------------------------------------------------------
// Per-node histogram + scan (A[v] = CSR start; A[N_NODES] = E).
// ---------------------------------------------------------------------------
__global__ __launch_bounds__(256) void k_zero_counts(int* __restrict__ counts)
{
    int i = blockIdx.x * 256 + threadIdx.x;
    if (i < N_NODES) counts[i] = 0;
}

__global__ __launch_bounds__(256) void k_hist(
    const int* __restrict__ dst, int* __restrict__ counts)
{
    int e = blockIdx.x * 256 + threadIdx.x;
    if (e < N_EDGES) atomicAdd(&counts[dst[e]], 1);
}

__global__ __launch_bounds__(1024) void k_scan(
    const int* __restrict__ counts, int* __restrict__ A)
{
    __shared__ int lds[17];
    const int tid = threadIdx.x, lane = tid & 63, wid = tid >> 6;
    int carry = 0;
    const int nchunk = (N_NODES + 1023) / 1024;
    for (int chunk = 0; chunk < nchunk; ++chunk) {
        int i = chunk * 1024 + tid;
        int c = (i < N_NODES) ? counts[i] : 0;
        int incl = c;
#pragma unroll
        for (int off = 1; off < 64; off <<= 1) {
            int t = __shfl_up(incl, off, 64);
            if (lane >= off) incl += t;
        }
        if (lane == 63) lds[wid] = incl;
        __syncthreads();
        if (wid == 0 && lane < 16) {
            int s = lds[lane];
            int si = s;
#pragma unroll
            for (int off = 1; off < 16; off <<= 1) {
                int t = __shfl_up(si, off, 64);
                if (lane >= off) si += t;
            }
            lds[lane] = si - s;
            if (lane == 15) lds[16] = si;
        }
        __syncthreads();
        int excl = carry + lds[wid] + (incl - c);
        if (i < N_NODES) A[i] = excl;
        carry += lds[16];
        __syncthreads();
    }
    if (tid == 0) A[N_NODES] = carry;   // == N_EDGES
}

// C[b] = A[b*128]: coarse bucket base cursors.
__global__ __launch_bounds__(256) void k_initcur(
    const int* __restrict__ A, int* __restrict__ C)
{
    int b = blockIdx.x * 256 + threadIdx.x;
    if (b < NBKT) C[b] = A[b << 7];
}

// ---------------------------------------------------------------------------
// P1: coarse multisplit into 391 dst-buckets. Block = 2048-edge chunk.
// LDS hist -> one global atomicAdd per (chunk,bucket) reserves a contiguous
// run -> records written into block-private runs (lines written ~once).
// rec: [7:0]=dst&127, [23:8]=src, [27:24]=rel, [47:32]=norm bf16.
// ---------------------------------------------------------------------------
template<int IS_F32>
__global__ __launch_bounds__(256) void k_p1(
    const int* __restrict__ src, const int* __restrict__ dst,
    const int* __restrict__ rel, const void* __restrict__ norm_raw,
    int* __restrict__ C, unsigned long long* __restrict__ R,
    const int* __restrict__ flag)
{
    if (*flag != IS_F32) return;
    __shared__ int hist[NBKT];
    __shared__ int curs[NBKT];
    for (int i = threadIdx.x; i < NBKT; i += 256) hist[i] = 0;
    __syncthreads();

    const int e0 = blockIdx.x * P1_CHUNK;
    for (int i = threadIdx.x; i < P1_CHUNK; i += 256) {
        int e = e0 + i;
        if (e < N_EDGES) atomicAdd(&hist[dst[e] >> 7], 1);
    }
    __syncthreads();
    for (int b = threadIdx.x; b < NBKT; b += 256) {
        int h = hist[b];
        curs[b] = h ? atomicAdd(&C[b], h) : 0;
    }
    __syncthreads();
    for (int i = threadIdx.x; i < P1_CHUNK; i += 256) {
        int e = e0 + i;
        if (e >= N_EDGES) continue;
        int d = dst[e];
        int pos = atomicAdd(&curs[d >> 7], 1);
        unsigned short nb = f2bfbits(ldx<IS_F32>(norm_raw, e));
        unsigned long long rec =
              (unsigned long long)(d & 127)
            | ((unsigned long long)(unsigned)src[e] << 8)
            | ((unsigned long long)(unsigned)rel[e] << 24)
            | ((unsigned long long)nb << 32);
        R[pos] = rec;
    }
}

// ---------------------------------------------------------------------------
// P2: one block per bucket; place records at exact CSR position via LDS
// cursors. All writes land in the bucket's block-private span.
// packed = src | rel<<16  (= (rec>>8)&0xFFFFFF since bits 28..31 are 0).
// ---------------------------------------------------------------------------
__global__ __launch_bounds__(256) void k_p2(
    const int* __restrict__ A,
    const unsigned long long* __restrict__ R,
    unsigned* __restrict__ packed,
    unsigned short* __restrict__ normS)
{
    __shared__ int curs[128];
    if (threadIdx.x < 128) curs[threadIdx.x] = 0;
    __syncthreads();

    const int b  = blockIdx.x;
    const int n0 = b << 7;
    const int n1 = min(n0 + 128, N_NODES);
    const int c0 = A[n0], c1 = A[n1];

    for (int i = c0 + threadIdx.x; i < c1; i += 256) {
        unsigned long long rec = R[i];
        int nl = (int)(rec & 127);
        int pos = A[n0 + nl] + atomicAdd(&curs[nl], 1);
        packed[pos] = (unsigned)((rec >> 8) & 0xFFFFFFu);
        normS[pos]  = (unsigned short)(rec >> 32);
    }
}

// ---------------------------------------------------------------------------
// K1 (MFMA, proven): transformed[n][r][o] = sum_d h[n][d]*W[r][d][o].
// ---------------------------------------------------------------------------
template<int IS_F32>
__device__ __forceinline__ short8 load_afrag(const void* h_raw, int row, int quad, int half)
{
    short8 r;
    if (IS_F32) {
        const float4* p = (const float4*)((const char*)h_raw + (size_t)row * 256 + half * 128 + quad * 32);
        float4 f0 = p[0], f1 = p[1];
        float fv[8] = {f0.x, f0.y, f0.z, f0.w, f1.x, f1.y, f1.z, f1.w};
#pragma unroll
        for (int j = 0; j < 8; ++j) r[j] = (short)f2bfbits(fv[j]);
    } else {
        uint4 v = *(const uint4*)((const char*)h_raw + (size_t)row * 128 + half * 64 + quad * 16);
        __builtin_memcpy(&r, &v, 16);
    }
    return r;
}

template<int IS_F32>
__global__ __launch_bounds__(256) void k1_mfma(
    const void* __restrict__ h_raw,
    const void* __restrict__ w_raw,
    __hip_bfloat16* __restrict__ transformed,
    const int* __restrict__ flag)
{
    if (*flag != IS_F32) return;
    const int lane = threadIdx.x & 63;
    const int wave = threadIdx.x >> 6;
    const int n15  = lane & 15;
    const int quad = lane >> 4;
    const int rbase = blockIdx.y * 4;

    __shared__ short Wl[4 * 2 * 64 * 40];   // 40 KB

    for (int idx = threadIdx.x; idx < 4 * 64 * 64; idx += 256) {
        int o = idx & 63, d = (idx >> 6) & 63, rl = idx >> 12;
        float wv = ldx<IS_F32>(w_raw, (size_t)((rbase + rl) * 64 + d) * 64 + o);
        int c = d >> 5, q = (d >> 3) & 3, j = d & 7;
        Wl[((rl * 2 + c) * 64 + o) * 40 + q * 8 + j] = (short)f2bfbits(wv);
    }
    __syncthreads();

    const int node0 = blockIdx.x * 64 + wave * 16;
    if (node0 >= N_NODES) return;

    short8 a0 = load_afrag<IS_F32>(h_raw, node0 + n15, quad, 0);
    short8 a1 = load_afrag<IS_F32>(h_raw, node0 + n15, quad, 1);

    unsigned short* tb = (unsigned short*)transformed;

#pragma unroll
    for (int rl = 0; rl < 4; ++rl) {
        float4v acc[4];
#pragma unroll
        for (int t = 0; t < 4; ++t) acc[t] = (float4v){0.f, 0.f, 0.f, 0.f};

#pragma unroll
        for (int t = 0; t < 4; ++t) {
            const short8* b0 = (const short8*)&Wl[((rl * 2 + 0) * 64 + t * 16 + n15) * 40 + quad * 8];
            acc[t] = __builtin_amdgcn_mfma_f32_16x16x32_bf16(a0, *b0, acc[t], 0, 0, 0);
        }
#pragma unroll
        for (int t = 0; t < 4; ++t) {
            const short8* b1 = (const short8*)&Wl[((rl * 2 + 1) * 64 + t * 16 + n15) * 40 + quad * 8];
            acc[t] = __builtin_amdgcn_mfma_f32_16x16x32_bf16(a1, *b1, acc[t], 0, 0, 0);
        }

        const int r = rbase + rl;
#pragma unroll
        for (int t = 0; t < 4; ++t) {
#pragma unroll
            for (int i = 0; i < 4; ++i) {
                int node = node0 + quad * 4 + i;
                tb[((size_t)node * NREL + r) * DIM + t * 16 + n15] = f2bfbits(acc[t][i]);
            }
        }
    }
}

// ---------------------------------------------------------------------------
// K_ACC (proven): one wave per dst node; CSR range [A[v], A[v+1]).
// ---------------------------------------------------------------------------
template<int IS_F32>
__global__ __launch_bounds__(256) void k_acc(
    const unsigned* __restrict__ packed,
    const unsigned short* __restrict__ normS,
    const __hip_bfloat16* __restrict__ transformed,
    const int* __restrict__ A,
    void* __restrict__ out, const int* __restrict__ flag)
{
    if (*flag != IS_F32) return;
    const int lane = threadIdx.x & 63;
    const int v = blockIdx.x * 4 + (threadIdx.x >> 6);
    if (v >= N_NODES) return;

    const int start = __builtin_amdgcn_readfirstlane(A[v]);
    const int end   = __builtin_amdgcn_readfirstlane(A[v + 1]);

    const unsigned short* tb = (const unsigned short*)transformed;
    float a = 0.f;
    int i = start;
    for (; i + 2 <= end; i += 2) {
        unsigned u0 = packed[i], u1 = packed[i + 1];
        float n0 = bfbits2f(normS[i]), n1 = bfbits2f(normS[i + 1]);
        unsigned off0 = ((u0 & 0xFFFFu) * NREL + (u0 >> 16)) * DIM + lane;
        unsigned off1 = ((u1 & 0xFFFFu) * NREL + (u1 >> 16)) * DIM + lane;
        float t0 = bfbits2f(tb[off0]);
        float t1 = bfbits2f(tb[off1]);
        a = fmaf(t0, n0, a);
        a = fmaf(t1, n1, a);
    }
    if (i < end) {
        unsigned u0 = packed[i];
        float n0 = bfbits2f(normS[i]);
        unsigned off0 = ((u0 & 0xFFFFu) * NREL + (u0 >> 16)) * DIM + lane;
        a = fmaf(bfbits2f(tb[off0]), n0, a);
    }

    float r = fmaxf(a, 0.f);
    const size_t ob = (size_t)v * DIM + lane;
    if (IS_F32) {
        ((float*)out)[ob] = r;
    } else {
        ((unsigned short*)out)[ob] = f2bfbits(r);
    }
}

// ---------------------------------------------------------------------------
extern "C" void kernel_launch(void* const* d_in, const int* in_sizes, int n_in,
                              void* d_out, int out_size, void* d_ws, size_t ws_size,
                              hipStream_t stream)
{
    const void* h      = d_in[0];
    const void* weight = d_in[1];
    const void* norm   = d_in[2];
    const int* src = (const int*)d_in[3];
    const int* dst = (const int*)d_in[4];
    const int* rel = (const int*)d_in[5];

    // ws: flag(256) | A[50001] | C[391] | counts[50000] | packed u32[E]
    //     | normS u16[E] | transformed bf16[N*R*64]  (R u64[E] aliases
    //     transformed: consumed by k_p2 before k1_mfma writes — stream order)
    char* w = (char*)d_ws;
    int*   flag   = (int*)w;                    w += 256;
    int*   A      = (int*)w;                    w += 200192;
    int*   C      = (int*)w;                    w += 2048;
    int*   counts = (int*)w;                    w += 200192;
    unsigned* packed = (unsigned*)w;            w += (size_t)N_EDGES * 4;
    unsigned short* normS = (unsigned short*)w; w += (size_t)N_EDGES * 2;
    __hip_bfloat16* transformed = (__hip_bfloat16*)w;
    unsigned long long* R = (unsigned long long*)transformed;

    k_detect<<<1, 64, 0, stream>>>((const float*)norm, flag);

    k_zero_counts<<<196, 256, 0, stream>>>(counts);
    k_hist<<<6250, 256, 0, stream>>>(dst, counts);
    k_scan<<<1, 1024, 0, stream>>>(counts, A);
    k_initcur<<<2, 256, 0, stream>>>(A, C);

    k_p1<0><<<P1_GRID, 256, 0, stream>>>(src, dst, rel, norm, C, R, flag);
    k_p1<1><<<P1_GRID, 256, 0, stream>>>(src, dst, rel, norm, C, R, flag);
    k_p2<<<NBKT, 256, 0, stream>>>(A, R, packed, normS);

    dim3 g1((N_NODES + 63) / 64, 4);
    k1_mfma<0><<<g1, 256, 0, stream>>>(h, weight, transformed, flag);
    k1_mfma<1><<<g1, 256, 0, stream>>>(h, weight, transformed, flag);

    k_acc<0><<<12500, 256, 0, stream>>>(packed, normS, transformed, A, d_out, flag);
    k_acc<1><<<12500, 256, 0, stream>>>(packed, normS, transformed, A, d_out, flag);
}

// Round 6
// 358.505 us; speedup vs baseline: 1.9114x; 1.2551x over previous
//
#include <hip/hip_runtime.h>
#include <hip/hip_bf16.h>

#define N_NODES 50000
#define N_EDGES 1600000
#define NREL    16
#define DIM     64

#define NBKT    391           // ceil(50000/128) buckets of 128 dst nodes
#define P1_CHUNK 2048
#define P1_GRID  782          // ceil(1.6M/2048)

typedef __attribute__((ext_vector_type(8))) short short8;
typedef __attribute__((ext_vector_type(4))) float float4v;

template<int IS_F32>
__device__ __forceinline__ float ldx(const void* p, size_t i) {
    if (IS_F32) {
        return ((const float*)p)[i];
    } else {
        unsigned short u = ((const unsigned short*)p)[i];
        return __uint_as_float(((unsigned)u) << 16);
    }
}

__device__ __forceinline__ float bfbits2f(unsigned short u) {
    return __uint_as_float(((unsigned)u) << 16);
}

__device__ __forceinline__ unsigned short f2bfbits(float v) {
    __hip_bfloat16 b = __float2bfloat16(v);
    unsigned short us; __builtin_memcpy(&us, &b, 2);
    return us;
}

// ---------------------------------------------------------------------------
// Dtype detector, parallel: 1024 threads check 1 word each (same predicate as
// the proven serial version). flag=1 if f32 dataset, 0 if bf16.
// ---------------------------------------------------------------------------
__global__ __launch_bounds__(1024) void k_detect(
    const float* __restrict__ norm_f, int* __restrict__ flag)
{
    __shared__ int sbad;
    if (threadIdx.x == 0) sbad = 0;
    __syncthreads();
    float v = norm_f[threadIdx.x];
    int bad = (v != v || fabsf(v) > 1e3f) ? 1 : 0;
    if (bad) atomicOr(&sbad, 1);
    __syncthreads();
    if (threadIdx.x == 0) *flag = sbad ? 0 : 1;
}

// ---------------------------------------------------------------------------
// Per-node histogram + scan (A[v] = CSR start; A[N_NODES] = E).
// ---------------------------------------------------------------------------
__global__ __launch_bounds__(256) void k_zero_counts(int* __restrict__ counts)
{
    int i = blockIdx.x * 256 + threadIdx.x;
    if (i < N_NODES) counts[i] = 0;
}

__global__ __launch_bounds__(256) void k_hist(
    const int* __restrict__ dst, int* __restrict__ counts)
{
    int e = blockIdx.x * 256 + threadIdx.x;
    if (e < N_EDGES) atomicAdd(&counts[dst[e]], 1);
}

__global__ __launch_bounds__(1024) void k_scan(
    const int* __restrict__ counts, int* __restrict__ A)
{
    __shared__ int lds[17];
    const int tid = threadIdx.x, lane = tid & 63, wid = tid >> 6;
    int carry = 0;
    const int nchunk = (N_NODES + 1023) / 1024;
    for (int chunk = 0; chunk < nchunk; ++chunk) {
        int i = chunk * 1024 + tid;
        int c = (i < N_NODES) ? counts[i] : 0;
        int incl = c;
#pragma unroll
        for (int off = 1; off < 64; off <<= 1) {
            int t = __shfl_up(incl, off, 64);
            if (lane >= off) incl += t;
        }
        if (lane == 63) lds[wid] = incl;
        __syncthreads();
        if (wid == 0 && lane < 16) {
            int s = lds[lane];
            int si = s;
#pragma unroll
            for (int off = 1; off < 16; off <<= 1) {
                int t = __shfl_up(si, off, 64);
                if (lane >= off) si += t;
            }
            lds[lane] = si - s;
            if (lane == 15) lds[16] = si;
        }
        __syncthreads();
        int excl = carry + lds[wid] + (incl - c);
        if (i < N_NODES) A[i] = excl;
        carry += lds[16];
        __syncthreads();
    }
    if (tid == 0) A[N_NODES] = carry;   // == N_EDGES
}

// C[b] = A[b*128]: coarse bucket base cursors.
__global__ __launch_bounds__(256) void k_initcur(
    const int* __restrict__ A, int* __restrict__ C)
{
    int b = blockIdx.x * 256 + threadIdx.x;
    if (b < NBKT) C[b] = A[b << 7];
}

// ---------------------------------------------------------------------------
// P1: coarse multisplit into 391 dst-buckets (proven). Single kernel; dtype
// branch is wave-uniform on *flag.
// rec: [7:0]=dst&127, [23:8]=src, [27:24]=rel, [47:32]=norm bf16.
// ---------------------------------------------------------------------------
template<int IS_F32>
__device__ __forceinline__ void p1_body(
    const int* __restrict__ src, const int* __restrict__ dst,
    const int* __restrict__ rel, const void* __restrict__ norm_raw,
    int* __restrict__ C, unsigned long long* __restrict__ R,
    int* hist, int* curs)
{
    for (int i = threadIdx.x; i < NBKT; i += 256) hist[i] = 0;
    __syncthreads();

    const int e0 = blockIdx.x * P1_CHUNK;
    for (int i = threadIdx.x; i < P1_CHUNK; i += 256) {
        int e = e0 + i;
        if (e < N_EDGES) atomicAdd(&hist[dst[e] >> 7], 1);
    }
    __syncthreads();
    for (int b = threadIdx.x; b < NBKT; b += 256) {
        int h = hist[b];
        curs[b] = h ? atomicAdd(&C[b], h) : 0;
    }
    __syncthreads();
    for (int i = threadIdx.x; i < P1_CHUNK; i += 256) {
        int e = e0 + i;
        if (e >= N_EDGES) continue;
        int d = dst[e];
        int pos = atomicAdd(&curs[d >> 7], 1);
        unsigned short nb = f2bfbits(ldx<IS_F32>(norm_raw, e));
        unsigned long long rec =
              (unsigned long long)(d & 127)
            | ((unsigned long long)(unsigned)src[e] << 8)
            | ((unsigned long long)(unsigned)rel[e] << 24)
            | ((unsigned long long)nb << 32);
        R[pos] = rec;
    }
}

__global__ __launch_bounds__(256) void k_p1(
    const int* __restrict__ src, const int* __restrict__ dst,
    const int* __restrict__ rel, const void* __restrict__ norm_raw,
    int* __restrict__ C, unsigned long long* __restrict__ R,
    const int* __restrict__ flag)
{
    __shared__ int hist[NBKT];
    __shared__ int curs[NBKT];
    if (*flag) p1_body<1>(src, dst, rel, norm_raw, C, R, hist, curs);
    else       p1_body<0>(src, dst, rel, norm_raw, C, R, hist, curs);
}

// ---------------------------------------------------------------------------
// P2 (proven): one block per bucket; exact CSR placement via LDS cursors.
// ---------------------------------------------------------------------------
__global__ __launch_bounds__(256) void k_p2(
    const int* __restrict__ A,
    const unsigned long long* __restrict__ R,
    unsigned* __restrict__ packed,
    unsigned short* __restrict__ normS)
{
    __shared__ int curs[128];
    if (threadIdx.x < 128) curs[threadIdx.x] = 0;
    __syncthreads();

    const int b  = blockIdx.x;
    const int n0 = b << 7;
    const int n1 = min(n0 + 128, N_NODES);
    const int c0 = A[n0], c1 = A[n1];

    for (int i = c0 + threadIdx.x; i < c1; i += 256) {
        unsigned long long rec = R[i];
        int nl = (int)(rec & 127);
        int pos = A[n0 + nl] + atomicAdd(&curs[nl], 1);
        packed[pos] = (unsigned)((rec >> 8) & 0xFFFFFFu);
        normS[pos]  = (unsigned short)(rec >> 32);
    }
}

// ---------------------------------------------------------------------------
// K1 (MFMA, proven): transformed[n][r][o] = sum_d h[n][d]*W[r][d][o].
// ---------------------------------------------------------------------------
template<int IS_F32>
__device__ __forceinline__ short8 load_afrag(const void* h_raw, int row, int quad, int half)
{
    short8 r;
    if (IS_F32) {
        const float4* p = (const float4*)((const char*)h_raw + (size_t)row * 256 + half * 128 + quad * 32);
        float4 f0 = p[0], f1 = p[1];
        float fv[8] = {f0.x, f0.y, f0.z, f0.w, f1.x, f1.y, f1.z, f1.w};
#pragma unroll
        for (int j = 0; j < 8; ++j) r[j] = (short)f2bfbits(fv[j]);
    } else {
        uint4 v = *(const uint4*)((const char*)h_raw + (size_t)row * 128 + half * 64 + quad * 16);
        __builtin_memcpy(&r, &v, 16);
    }
    return r;
}

template<int IS_F32>
__device__ __forceinline__ void mfma_body(
    const void* __restrict__ h_raw,
    const void* __restrict__ w_raw,
    __hip_bfloat16* __restrict__ transformed,
    short* Wl)
{
    const int lane = threadIdx.x & 63;
    const int wave = threadIdx.x >> 6;
    const int n15  = lane & 15;
    const int quad = lane >> 4;
    const int rbase = blockIdx.y * 4;

    for (int idx = threadIdx.x; idx < 4 * 64 * 64; idx += 256) {
        int o = idx & 63, d = (idx >> 6) & 63, rl = idx >> 12;
        float wv = ldx<IS_F32>(w_raw, (size_t)((rbase + rl) * 64 + d) * 64 + o);
        int c = d >> 5, q = (d >> 3) & 3, j = d & 7;
        Wl[((rl * 2 + c) * 64 + o) * 40 + q * 8 + j] = (short)f2bfbits(wv);
    }
    __syncthreads();

    const int node0 = blockIdx.x * 64 + wave * 16;
    if (node0 >= N_NODES) return;

    short8 a0 = load_afrag<IS_F32>(h_raw, node0 + n15, quad, 0);
    short8 a1 = load_afrag<IS_F32>(h_raw, node0 + n15, quad, 1);

    unsigned short* tb = (unsigned short*)transformed;

#pragma unroll
    for (int rl = 0; rl < 4; ++rl) {
        float4v acc[4];
#pragma unroll
        for (int t = 0; t < 4; ++t) acc[t] = (float4v){0.f, 0.f, 0.f, 0.f};

#pragma unroll
        for (int t = 0; t < 4; ++t) {
            const short8* b0 = (const short8*)&Wl[((rl * 2 + 0) * 64 + t * 16 + n15) * 40 + quad * 8];
            acc[t] = __builtin_amdgcn_mfma_f32_16x16x32_bf16(a0, *b0, acc[t], 0, 0, 0);
        }
#pragma unroll
        for (int t = 0; t < 4; ++t) {
            const short8* b1 = (const short8*)&Wl[((rl * 2 + 1) * 64 + t * 16 + n15) * 40 + quad * 8];
            acc[t] = __builtin_amdgcn_mfma_f32_16x16x32_bf16(a1, *b1, acc[t], 0, 0, 0);
        }

        const int r = rbase + rl;
#pragma unroll
        for (int t = 0; t < 4; ++t) {
#pragma unroll
            for (int i = 0; i < 4; ++i) {
                int node = node0 + quad * 4 + i;
                tb[((size_t)node * NREL + r) * DIM + t * 16 + n15] = f2bfbits(acc[t][i]);
            }
        }
    }
}

__global__ __launch_bounds__(256) void k1_mfma(
    const void* __restrict__ h_raw,
    const void* __restrict__ w_raw,
    __hip_bfloat16* __restrict__ transformed,
    const int* __restrict__ flag)
{
    __shared__ short Wl[4 * 2 * 64 * 40];   // 40 KB
    if (*flag) mfma_body<1>(h_raw, w_raw, transformed, Wl);
    else       mfma_body<0>(h_raw, w_raw, transformed, Wl);
}

// ---------------------------------------------------------------------------
// K_ACC (proven): one wave per dst node; CSR range [A[v], A[v+1]).
// ---------------------------------------------------------------------------
template<int IS_F32>
__device__ __forceinline__ void acc_body(
    const unsigned* __restrict__ packed,
    const unsigned short* __restrict__ normS,
    const __hip_bfloat16* __restrict__ transformed,
    const int* __restrict__ A,
    void* __restrict__ out)
{
    const int lane = threadIdx.x & 63;
    const int v = blockIdx.x * 4 + (threadIdx.x >> 6);
    if (v >= N_NODES) return;

    const int start = __builtin_amdgcn_readfirstlane(A[v]);
    const int end   = __builtin_amdgcn_readfirstlane(A[v + 1]);

    const unsigned short* tb = (const unsigned short*)transformed;
    float a = 0.f;
    int i = start;
    for (; i + 2 <= end; i += 2) {
        unsigned u0 = packed[i], u1 = packed[i + 1];
        float n0 = bfbits2f(normS[i]), n1 = bfbits2f(normS[i + 1]);
        unsigned off0 = ((u0 & 0xFFFFu) * NREL + (u0 >> 16)) * DIM + lane;
        unsigned off1 = ((u1 & 0xFFFFu) * NREL + (u1 >> 16)) * DIM + lane;
        float t0 = bfbits2f(tb[off0]);
        float t1 = bfbits2f(tb[off1]);
        a = fmaf(t0, n0, a);
        a = fmaf(t1, n1, a);
    }
    if (i < end) {
        unsigned u0 = packed[i];
        float n0 = bfbits2f(normS[i]);
        unsigned off0 = ((u0 & 0xFFFFu) * NREL + (u0 >> 16)) * DIM + lane;
        a = fmaf(bfbits2f(tb[off0]), n0, a);
    }

    float r = fmaxf(a, 0.f);
    const size_t ob = (size_t)v * DIM + lane;
    if (IS_F32) {
        ((float*)out)[ob] = r;
    } else {
        ((unsigned short*)out)[ob] = f2bfbits(r);
    }
}

__global__ __launch_bounds__(256) void k_acc(
    const unsigned* __restrict__ packed,
    const unsigned short* __restrict__ normS,
    const __hip_bfloat16* __restrict__ transformed,
    const int* __restrict__ A,
    void* __restrict__ out, const int* __restrict__ flag)
{
    if (*flag) acc_body<1>(packed, normS, transformed, A, out);
    else       acc_body<0>(packed, normS, transformed, A, out);
}

// ---------------------------------------------------------------------------
extern "C" void kernel_launch(void* const* d_in, const int* in_sizes, int n_in,
                              void* d_out, int out_size, void* d_ws, size_t ws_size,
                              hipStream_t stream)
{
    const void* h      = d_in[0];
    const void* weight = d_in[1];
    const void* norm   = d_in[2];
    const int* src = (const int*)d_in[3];
    const int* dst = (const int*)d_in[4];
    const int* rel = (const int*)d_in[5];

    // ws: flag(256) | A[50001] | C[391] | counts[50000] | packed u32[E]
    //     | normS u16[E] | transformed bf16[N*R*64]  (R u64[E] aliases
    //     transformed: consumed by k_p2 before k1_mfma writes — stream order)
    char* w = (char*)d_ws;
    int*   flag   = (int*)w;                    w += 256;
    int*   A      = (int*)w;                    w += 200192;
    int*   C      = (int*)w;                    w += 2048;
    int*   counts = (int*)w;                    w += 200192;
    unsigned* packed = (unsigned*)w;            w += (size_t)N_EDGES * 4;
    unsigned short* normS = (unsigned short*)w; w += (size_t)N_EDGES * 2;
    __hip_bfloat16* transformed = (__hip_bfloat16*)w;
    unsigned long long* R = (unsigned long long*)transformed;

    k_detect<<<1, 1024, 0, stream>>>((const float*)norm, flag);

    k_zero_counts<<<196, 256, 0, stream>>>(counts);
    k_hist<<<6250, 256, 0, stream>>>(dst, counts);
    k_scan<<<1, 1024, 0, stream>>>(counts, A);
    k_initcur<<<2, 256, 0, stream>>>(A, C);

    k_p1<<<P1_GRID, 256, 0, stream>>>(src, dst, rel, norm, C, R, flag);
    k_p2<<<NBKT, 256, 0, stream>>>(A, R, packed, normS);

    dim3 g1((N_NODES + 63) / 64, 4);
    k1_mfma<<<g1, 256, 0, stream>>>(h, weight, transformed, flag);

    k_acc<<<12500, 256, 0, stream>>>(packed, normS, transformed, A, d_out, flag);
}

// Round 7
// 281.527 us; speedup vs baseline: 2.4340x; 1.2734x over previous
//
#include <hip/hip_runtime.h>
#include <hip/hip_bf16.h>

#define N_NODES 50000
#define N_EDGES 1600000
#define NREL    16
#define DIM     64

#define NBKT    391           // ceil(50000/128) buckets of 128 dst nodes
#define P1_CHUNK 2048
#define P1_GRID  782          // ceil(1.6M/2048)

typedef __attribute__((ext_vector_type(8))) short short8;
typedef __attribute__((ext_vector_type(4))) float float4v;

template<int IS_F32>
__device__ __forceinline__ float ldx(const void* p, size_t i) {
    if (IS_F32) {
        return ((const float*)p)[i];
    } else {
        unsigned short u = ((const unsigned short*)p)[i];
        return __uint_as_float(((unsigned)u) << 16);
    }
}

__device__ __forceinline__ float bfbits2f(unsigned short u) {
    return __uint_as_float(((unsigned)u) << 16);
}

__device__ __forceinline__ unsigned short f2bfbits(float v) {
    __hip_bfloat16 b = __float2bfloat16(v);
    unsigned short us; __builtin_memcpy(&us, &b, 2);
    return us;
}

// ---------------------------------------------------------------------------
// Dtype detector (proven): flag=1 if f32 dataset, 0 if bf16.
// ---------------------------------------------------------------------------
__global__ __launch_bounds__(1024) void k_detect(
    const float* __restrict__ norm_f, int* __restrict__ flag)
{
    __shared__ int sbad;
    if (threadIdx.x == 0) sbad = 0;
    __syncthreads();
    float v = norm_f[threadIdx.x];
    int bad = (v != v || fabsf(v) > 1e3f) ? 1 : 0;
    if (bad) atomicOr(&sbad, 1);
    __syncthreads();
    if (threadIdx.x == 0) *flag = sbad ? 0 : 1;
}

// ---------------------------------------------------------------------------
// Bucket histogram, atomic-free at global scope: LDS hist per 2048-edge
// chunk, contiguous row write H[blk][b].
// ---------------------------------------------------------------------------
__global__ __launch_bounds__(256) void k_bhist(
    const int* __restrict__ dst, int* __restrict__ H)
{
    __shared__ int hist[NBKT];
    for (int i = threadIdx.x; i < NBKT; i += 256) hist[i] = 0;
    __syncthreads();
    const int e0 = blockIdx.x * P1_CHUNK;
    for (int i = threadIdx.x; i < P1_CHUNK; i += 256) {
        int e = e0 + i;
        if (e < N_EDGES) atomicAdd(&hist[dst[e] >> 7], 1);
    }
    __syncthreads();
    for (int b = threadIdx.x; b < NBKT; b += 256)
        H[blockIdx.x * NBKT + b] = hist[b];
}

// One block per bucket b: exclusive-scan column H[:,b] over the 782 chunks
// -> OT[b][blk] (contiguous), and tot[b] = column total.
__global__ __launch_bounds__(256) void k_bscan1(
    const int* __restrict__ H, int* __restrict__ OT, int* __restrict__ tot)
{
    __shared__ int col[P1_GRID];
    const int b = blockIdx.x;
    for (int i = threadIdx.x; i < P1_GRID; i += 256)
        col[i] = H[i * NBKT + b];
    __syncthreads();
    if (threadIdx.x < 64) {
        const int lane = threadIdx.x;
        int carry = 0;
        for (int chunk = 0; chunk < (P1_GRID + 63) / 64; ++chunk) {
            int i = chunk * 64 + lane;
            int c = (i < P1_GRID) ? col[i] : 0;
            int incl = c;
#pragma unroll
            for (int off = 1; off < 64; off <<= 1) {
                int t = __shfl_up(incl, off, 64);
                if (lane >= off) incl += t;
            }
            if (i < P1_GRID) col[i] = carry + incl - c;
            carry += __shfl(incl, 63, 64);
        }
        if (lane == 0) tot[b] = carry;
    }
    __syncthreads();
    for (int i = threadIdx.x; i < P1_GRID; i += 256)
        OT[(size_t)b * P1_GRID + i] = col[i];
}

// Single block: exclusive-scan tot[391] -> base[0..390], base[391] = E.
__global__ __launch_bounds__(64) void k_bscan2(
    const int* __restrict__ tot, int* __restrict__ base)
{
    const int lane = threadIdx.x;
    int carry = 0;
    for (int chunk = 0; chunk < (NBKT + 63) / 64; ++chunk) {
        int i = chunk * 64 + lane;
        int c = (i < NBKT) ? tot[i] : 0;
        int incl = c;
#pragma unroll
        for (int off = 1; off < 64; off <<= 1) {
            int t = __shfl_up(incl, off, 64);
            if (lane >= off) incl += t;
        }
        if (i < NBKT) base[i] = carry + incl - c;
        carry += __shfl(incl, 63, 64);
    }
    if (lane == 0) base[NBKT] = carry;   // == N_EDGES
}

// ---------------------------------------------------------------------------
// P1: multisplit into bucket runs; cursors from base[b]+OT[b][blk] —
// deterministic reservation, LDS atomics only.
// rec: [7:0]=dst&127, [23:8]=src, [27:24]=rel, [47:32]=norm bf16.
// ---------------------------------------------------------------------------
template<int IS_F32>
__device__ __forceinline__ void p1_body(
    const int* __restrict__ src, const int* __restrict__ dst,
    const int* __restrict__ rel, const void* __restrict__ norm_raw,
    const int* __restrict__ base, const int* __restrict__ OT,
    unsigned long long* __restrict__ R, int* curs)
{
    const int blk = blockIdx.x;
    for (int b = threadIdx.x; b < NBKT; b += 256)
        curs[b] = base[b] + OT[(size_t)b * P1_GRID + blk];
    __syncthreads();
    const int e0 = blk * P1_CHUNK;
    for (int i = threadIdx.x; i < P1_CHUNK; i += 256) {
        int e = e0 + i;
        if (e >= N_EDGES) continue;
        int d = dst[e];
        int pos = atomicAdd(&curs[d >> 7], 1);
        unsigned short nb = f2bfbits(ldx<IS_F32>(norm_raw, e));
        unsigned long long rec =
              (unsigned long long)(d & 127)
            | ((unsigned long long)(unsigned)src[e] << 8)
            | ((unsigned long long)(unsigned)rel[e] << 24)
            | ((unsigned long long)nb << 32);
        R[pos] = rec;
    }
}

__global__ __launch_bounds__(256) void k_p1(
    const int* __restrict__ src, const int* __restrict__ dst,
    const int* __restrict__ rel, const void* __restrict__ norm_raw,
    const int* __restrict__ base, const int* __restrict__ OT,
    unsigned long long* __restrict__ R, const int* __restrict__ flag)
{
    __shared__ int curs[NBKT];
    if (*flag) p1_body<1>(src, dst, rel, norm_raw, base, OT, R, curs);
    else       p1_body<0>(src, dst, rel, norm_raw, base, OT, R, curs);
}

// ---------------------------------------------------------------------------
// P2: one block per bucket. Pass 1: LDS count of local node ids -> 128-wide
// exclusive scan -> writes A[n0..n1) (and A[N] for last bucket). Pass 2:
// exact CSR placement via LDS cursors (block-private span).
// ---------------------------------------------------------------------------
__global__ __launch_bounds__(256) void k_p2(
    const int* __restrict__ base,
    const unsigned long long* __restrict__ R,
    unsigned* __restrict__ packed,
    unsigned short* __restrict__ normS,
    int* __restrict__ A)
{
    __shared__ int cnt[128];
    __shared__ int Aex[128];
    __shared__ int curs[128];
    __shared__ int tot0s;
    const int tid = threadIdx.x;
    if (tid < 128) { cnt[tid] = 0; curs[tid] = 0; }
    __syncthreads();

    const int b  = blockIdx.x;
    const int n0 = b << 7;
    const int nn = min(128, N_NODES - n0);
    const int c0 = base[b], c1 = base[b + 1];

    for (int i = c0 + tid; i < c1; i += 256)
        atomicAdd(&cnt[(int)(R[i] & 127)], 1);
    __syncthreads();

    // exclusive scan of cnt[0..127] using two waves
    if (tid < 64) {
        int c = cnt[tid], incl = c;
#pragma unroll
        for (int off = 1; off < 64; off <<= 1) {
            int t = __shfl_up(incl, off, 64);
            if (tid >= off) incl += t;
        }
        Aex[tid] = c0 + incl - c;
        if (tid == 63) tot0s = incl;
    }
    __syncthreads();
    if (tid >= 64 && tid < 128) {
        int lane = tid - 64;
        int c = cnt[tid], incl = c;
#pragma unroll
        for (int off = 1; off < 64; off <<= 1) {
            int t = __shfl_up(incl, off, 64);
            if (lane >= off) incl += t;
        }
        Aex[tid] = c0 + tot0s + incl - c;
    }
    __syncthreads();

    if (tid < nn) A[n0 + tid] = Aex[tid];
    if (b == NBKT - 1 && tid == 0) A[N_NODES] = c1;

    for (int i = c0 + tid; i < c1; i += 256) {
        unsigned long long rec = R[i];
        int nl = (int)(rec & 127);
        int pos = Aex[nl] + atomicAdd(&curs[nl], 1);
        packed[pos] = (unsigned)((rec >> 8) & 0xFFFFFFu);
        normS[pos]  = (unsigned short)(rec >> 32);
    }
}

// ---------------------------------------------------------------------------
// K1 (MFMA, proven): transformed[n][r][o] = sum_d h[n][d]*W[r][d][o].
// ---------------------------------------------------------------------------
template<int IS_F32>
__device__ __forceinline__ short8 load_afrag(const void* h_raw, int row, int quad, int half)
{
    short8 r;
    if (IS_F32) {
        const float4* p = (const float4*)((const char*)h_raw + (size_t)row * 256 + half * 128 + quad * 32);
        float4 f0 = p[0], f1 = p[1];
        float fv[8] = {f0.x, f0.y, f0.z, f0.w, f1.x, f1.y, f1.z, f1.w};
#pragma unroll
        for (int j = 0; j < 8; ++j) r[j] = (short)f2bfbits(fv[j]);
    } else {
        uint4 v = *(const uint4*)((const char*)h_raw + (size_t)row * 128 + half * 64 + quad * 16);
        __builtin_memcpy(&r, &v, 16);
    }
    return r;
}

template<int IS_F32>
__device__ __forceinline__ void mfma_body(
    const void* __restrict__ h_raw,
    const void* __restrict__ w_raw,
    __hip_bfloat16* __restrict__ transformed,
    short* Wl)
{
    const int lane = threadIdx.x & 63;
    const int wave = threadIdx.x >> 6;
    const int n15  = lane & 15;
    const int quad = lane >> 4;
    const int rbase = blockIdx.y * 4;

    for (int idx = threadIdx.x; idx < 4 * 64 * 64; idx += 256) {
        int o = idx & 63, d = (idx >> 6) & 63, rl = idx >> 12;
        float wv = ldx<IS_F32>(w_raw, (size_t)((rbase + rl) * 64 + d) * 64 + o);
        int c = d >> 5, q = (d >> 3) & 3, j = d & 7;
        Wl[((rl * 2 + c) * 64 + o) * 40 + q * 8 + j] = (short)f2bfbits(wv);
    }
    __syncthreads();

    const int node0 = blockIdx.x * 64 + wave * 16;
    if (node0 >= N_NODES) return;

    short8 a0 = load_afrag<IS_F32>(h_raw, node0 + n15, quad, 0);
    short8 a1 = load_afrag<IS_F32>(h_raw, node0 + n15, quad, 1);

    unsigned short* tb = (unsigned short*)transformed;

#pragma unroll
    for (int rl = 0; rl < 4; ++rl) {
        float4v acc[4];
#pragma unroll
        for (int t = 0; t < 4; ++t) acc[t] = (float4v){0.f, 0.f, 0.f, 0.f};

#pragma unroll
        for (int t = 0; t < 4; ++t) {
            const short8* b0 = (const short8*)&Wl[((rl * 2 + 0) * 64 + t * 16 + n15) * 40 + quad * 8];
            acc[t] = __builtin_amdgcn_mfma_f32_16x16x32_bf16(a0, *b0, acc[t], 0, 0, 0);
        }
#pragma unroll
        for (int t = 0; t < 4; ++t) {
            const short8* b1 = (const short8*)&Wl[((rl * 2 + 1) * 64 + t * 16 + n15) * 40 + quad * 8];
            acc[t] = __builtin_amdgcn_mfma_f32_16x16x32_bf16(a1, *b1, acc[t], 0, 0, 0);
        }

        const int r = rbase + rl;
#pragma unroll
        for (int t = 0; t < 4; ++t) {
#pragma unroll
            for (int i = 0; i < 4; ++i) {
                int node = node0 + quad * 4 + i;
                tb[((size_t)node * NREL + r) * DIM + t * 16 + n15] = f2bfbits(acc[t][i]);
            }
        }
    }
}

__global__ __launch_bounds__(256) void k1_mfma(
    const void* __restrict__ h_raw,
    const void* __restrict__ w_raw,
    __hip_bfloat16* __restrict__ transformed,
    const int* __restrict__ flag)
{
    __shared__ short Wl[4 * 2 * 64 * 40];   // 40 KB
    if (*flag) mfma_body<1>(h_raw, w_raw, transformed, Wl);
    else       mfma_body<0>(h_raw, w_raw, transformed, Wl);
}

// ---------------------------------------------------------------------------
// K_ACC (proven): one wave per dst node; CSR range [A[v], A[v+1]).
// ---------------------------------------------------------------------------
template<int IS_F32>
__device__ __forceinline__ void acc_body(
    const unsigned* __restrict__ packed,
    const unsigned short* __restrict__ normS,
    const __hip_bfloat16* __restrict__ transformed,
    const int* __restrict__ A,
    void* __restrict__ out)
{
    const int lane = threadIdx.x & 63;
    const int v = blockIdx.x * 4 + (threadIdx.x >> 6);
    if (v >= N_NODES) return;

    const int start = __builtin_amdgcn_readfirstlane(A[v]);
    const int end   = __builtin_amdgcn_readfirstlane(A[v + 1]);

    const unsigned short* tb = (const unsigned short*)transformed;
    float a = 0.f;
    int i = start;
    for (; i + 2 <= end; i += 2) {
        unsigned u0 = packed[i], u1 = packed[i + 1];
        float n0 = bfbits2f(normS[i]), n1 = bfbits2f(normS[i + 1]);
        unsigned off0 = ((u0 & 0xFFFFu) * NREL + (u0 >> 16)) * DIM + lane;
        unsigned off1 = ((u1 & 0xFFFFu) * NREL + (u1 >> 16)) * DIM + lane;
        float t0 = bfbits2f(tb[off0]);
        float t1 = bfbits2f(tb[off1]);
        a = fmaf(t0, n0, a);
        a = fmaf(t1, n1, a);
    }
    if (i < end) {
        unsigned u0 = packed[i];
        float n0 = bfbits2f(normS[i]);
        unsigned off0 = ((u0 & 0xFFFFu) * NREL + (u0 >> 16)) * DIM + lane;
        a = fmaf(bfbits2f(tb[off0]), n0, a);
    }

    float r = fmaxf(a, 0.f);
    const size_t ob = (size_t)v * DIM + lane;
    if (IS_F32) {
        ((float*)out)[ob] = r;
    } else {
        ((unsigned short*)out)[ob] = f2bfbits(r);
    }
}

__global__ __launch_bounds__(256) void k_acc(
    const unsigned* __restrict__ packed,
    const unsigned short* __restrict__ normS,
    const __hip_bfloat16* __restrict__ transformed,
    const int* __restrict__ A,
    void* __restrict__ out, const int* __restrict__ flag)
{
    if (*flag) acc_body<1>(packed, normS, transformed, A, out);
    else       acc_body<0>(packed, normS, transformed, A, out);
}

// ---------------------------------------------------------------------------
extern "C" void kernel_launch(void* const* d_in, const int* in_sizes, int n_in,
                              void* d_out, int out_size, void* d_ws, size_t ws_size,
                              hipStream_t stream)
{
    const void* h      = d_in[0];
    const void* weight = d_in[1];
    const void* norm   = d_in[2];
    const int* src = (const int*)d_in[3];
    const int* dst = (const int*)d_in[4];
    const int* rel = (const int*)d_in[5];

    // ws: flag(256) | A[50001] | base[392]+tot[391] | H[782*391] | OT[391*782]
    //     | packed u32[E] | normS u16[E] | transformed bf16[N*R*64]
    //     (R u64[E] aliases transformed; consumed by k_p2 before k1_mfma)
    char* w = (char*)d_ws;
    int*   flag = (int*)w;                      w += 256;
    int*   A    = (int*)w;                      w += 200192;
    int*   base = (int*)w;                      w += 2048;
    int*   tot  = (int*)w;                      w += 2048;
    int*   H    = (int*)w;                      w += (size_t)P1_GRID * NBKT * 4;   // 1.22 MB
    int*   OT   = (int*)w;                      w += (size_t)NBKT * P1_GRID * 4;   // 1.22 MB
    unsigned* packed = (unsigned*)w;            w += (size_t)N_EDGES * 4;
    unsigned short* normS = (unsigned short*)w; w += (size_t)N_EDGES * 2;
    __hip_bfloat16* transformed = (__hip_bfloat16*)w;
    unsigned long long* R = (unsigned long long*)transformed;

    k_detect<<<1, 1024, 0, stream>>>((const float*)norm, flag);

    k_bhist<<<P1_GRID, 256, 0, stream>>>(dst, H);
    k_bscan1<<<NBKT, 256, 0, stream>>>(H, OT, tot);
    k_bscan2<<<1, 64, 0, stream>>>(tot, base);

    k_p1<<<P1_GRID, 256, 0, stream>>>(src, dst, rel, norm, base, OT, R, flag);
    k_p2<<<NBKT, 256, 0, stream>>>(base, R, packed, normS, A);

    dim3 g1((N_NODES + 63) / 64, 4);
    k1_mfma<<<g1, 256, 0, stream>>>(h, weight, transformed, flag);

    k_acc<<<12500, 256, 0, stream>>>(packed, normS, transformed, A, d_out, flag);
}

// Round 8
// 257.593 us; speedup vs baseline: 2.6601x; 1.0929x over previous
//
#include <hip/hip_runtime.h>
#include <hip/hip_bf16.h>

#define N_NODES 50000
#define N_EDGES 1600000
#define NREL    16
#define DIM     64

#define NBKT    391           // ceil(50000/128) buckets of 128 dst nodes
#define P1_CHUNK 2048
#define P1_GRID  782          // ceil(1.6M/2048)

typedef __attribute__((ext_vector_type(8))) short short8;
typedef __attribute__((ext_vector_type(4))) float float4v;

template<int IS_F32>
__device__ __forceinline__ float ldx(const void* p, size_t i) {
    if (IS_F32) {
        return ((const float*)p)[i];
    } else {
        unsigned short u = ((const unsigned short*)p)[i];
        return __uint_as_float(((unsigned)u) << 16);
    }
}

__device__ __forceinline__ float bfbits2f(unsigned short u) {
    return __uint_as_float(((unsigned)u) << 16);
}

__device__ __forceinline__ unsigned short f2bfbits(float v) {
    __hip_bfloat16 b = __float2bfloat16(v);
    unsigned short us; __builtin_memcpy(&us, &b, 2);
    return us;
}

// ---------------------------------------------------------------------------
// Dtype detector (proven): flag=1 if f32 dataset, 0 if bf16.
// ---------------------------------------------------------------------------
__global__ __launch_bounds__(1024) void k_detect(
    const float* __restrict__ norm_f, int* __restrict__ flag)
{
    __shared__ int sbad;
    if (threadIdx.x == 0) sbad = 0;
    __syncthreads();
    float v = norm_f[threadIdx.x];
    int bad = (v != v || fabsf(v) > 1e3f) ? 1 : 0;
    if (bad) atomicOr(&sbad, 1);
    __syncthreads();
    if (threadIdx.x == 0) *flag = sbad ? 0 : 1;
}

// ---------------------------------------------------------------------------
// Bucket histogram (proven, atomic-free at global scope).
// ---------------------------------------------------------------------------
__global__ __launch_bounds__(256) void k_bhist(
    const int* __restrict__ dst, int* __restrict__ H)
{
    __shared__ int hist[NBKT];
    for (int i = threadIdx.x; i < NBKT; i += 256) hist[i] = 0;
    __syncthreads();
    const int e0 = blockIdx.x * P1_CHUNK;
    for (int i = threadIdx.x; i < P1_CHUNK; i += 256) {
        int e = e0 + i;
        if (e < N_EDGES) atomicAdd(&hist[dst[e] >> 7], 1);
    }
    __syncthreads();
    for (int b = threadIdx.x; b < NBKT; b += 256)
        H[blockIdx.x * NBKT + b] = hist[b];
}

__global__ __launch_bounds__(256) void k_bscan1(
    const int* __restrict__ H, int* __restrict__ OT, int* __restrict__ tot)
{
    __shared__ int col[P1_GRID];
    const int b = blockIdx.x;
    for (int i = threadIdx.x; i < P1_GRID; i += 256)
        col[i] = H[i * NBKT + b];
    __syncthreads();
    if (threadIdx.x < 64) {
        const int lane = threadIdx.x;
        int carry = 0;
        for (int chunk = 0; chunk < (P1_GRID + 63) / 64; ++chunk) {
            int i = chunk * 64 + lane;
            int c = (i < P1_GRID) ? col[i] : 0;
            int incl = c;
#pragma unroll
            for (int off = 1; off < 64; off <<= 1) {
                int t = __shfl_up(incl, off, 64);
                if (lane >= off) incl += t;
            }
            if (i < P1_GRID) col[i] = carry + incl - c;
            carry += __shfl(incl, 63, 64);
        }
        if (lane == 0) tot[b] = carry;
    }
    __syncthreads();
    for (int i = threadIdx.x; i < P1_GRID; i += 256)
        OT[(size_t)b * P1_GRID + i] = col[i];
}

__global__ __launch_bounds__(64) void k_bscan2(
    const int* __restrict__ tot, int* __restrict__ base)
{
    const int lane = threadIdx.x;
    int carry = 0;
    for (int chunk = 0; chunk < (NBKT + 63) / 64; ++chunk) {
        int i = chunk * 64 + lane;
        int c = (i < NBKT) ? tot[i] : 0;
        int incl = c;
#pragma unroll
        for (int off = 1; off < 64; off <<= 1) {
            int t = __shfl_up(incl, off, 64);
            if (lane >= off) incl += t;
        }
        if (i < NBKT) base[i] = carry + incl - c;
        carry += __shfl(incl, 63, 64);
    }
    if (lane == 0) base[NBKT] = carry;   // == N_EDGES
}

// ---------------------------------------------------------------------------
// P1 (proven): multisplit into bucket runs, deterministic reservation.
// rec: [7:0]=dst&127, [23:8]=src, [27:24]=rel, [47:32]=norm bf16.
// ---------------------------------------------------------------------------
template<int IS_F32>
__device__ __forceinline__ void p1_body(
    const int* __restrict__ src, const int* __restrict__ dst,
    const int* __restrict__ rel, const void* __restrict__ norm_raw,
    const int* __restrict__ base, const int* __restrict__ OT,
    unsigned long long* __restrict__ R, int* curs)
{
    const int blk = blockIdx.x;
    for (int b = threadIdx.x; b < NBKT; b += 256)
        curs[b] = base[b] + OT[(size_t)b * P1_GRID + blk];
    __syncthreads();
    const int e0 = blk * P1_CHUNK;
    for (int i = threadIdx.x; i < P1_CHUNK; i += 256) {
        int e = e0 + i;
        if (e >= N_EDGES) continue;
        int d = dst[e];
        int pos = atomicAdd(&curs[d >> 7], 1);
        unsigned short nb = f2bfbits(ldx<IS_F32>(norm_raw, e));
        unsigned long long rec =
              (unsigned long long)(d & 127)
            | ((unsigned long long)(unsigned)src[e] << 8)
            | ((unsigned long long)(unsigned)rel[e] << 24)
            | ((unsigned long long)nb << 32);
        R[pos] = rec;
    }
}

__global__ __launch_bounds__(256) void k_p1(
    const int* __restrict__ src, const int* __restrict__ dst,
    const int* __restrict__ rel, const void* __restrict__ norm_raw,
    const int* __restrict__ base, const int* __restrict__ OT,
    unsigned long long* __restrict__ R, const int* __restrict__ flag)
{
    __shared__ int curs[NBKT];
    if (*flag) p1_body<1>(src, dst, rel, norm_raw, base, OT, R, curs);
    else       p1_body<0>(src, dst, rel, norm_raw, base, OT, R, curs);
}

// ---------------------------------------------------------------------------
// P2 (proven): per-bucket exact CSR placement + A[] emission.
// ---------------------------------------------------------------------------
__global__ __launch_bounds__(256) void k_p2(
    const int* __restrict__ base,
    const unsigned long long* __restrict__ R,
    unsigned* __restrict__ packed,
    unsigned short* __restrict__ normS,
    int* __restrict__ A)
{
    __shared__ int cnt[128];
    __shared__ int Aex[128];
    __shared__ int curs[128];
    __shared__ int tot0s;
    const int tid = threadIdx.x;
    if (tid < 128) { cnt[tid] = 0; curs[tid] = 0; }
    __syncthreads();

    const int b  = blockIdx.x;
    const int n0 = b << 7;
    const int nn = min(128, N_NODES - n0);
    const int c0 = base[b], c1 = base[b + 1];

    for (int i = c0 + tid; i < c1; i += 256)
        atomicAdd(&cnt[(int)(R[i] & 127)], 1);
    __syncthreads();

    if (tid < 64) {
        int c = cnt[tid], incl = c;
#pragma unroll
        for (int off = 1; off < 64; off <<= 1) {
            int t = __shfl_up(incl, off, 64);
            if (tid >= off) incl += t;
        }
        Aex[tid] = c0 + incl - c;
        if (tid == 63) tot0s = incl;
    }
    __syncthreads();
    if (tid >= 64 && tid < 128) {
        int lane = tid - 64;
        int c = cnt[tid], incl = c;
#pragma unroll
        for (int off = 1; off < 64; off <<= 1) {
            int t = __shfl_up(incl, off, 64);
            if (lane >= off) incl += t;
        }
        Aex[tid] = c0 + tot0s + incl - c;
    }
    __syncthreads();

    if (tid < nn) A[n0 + tid] = Aex[tid];
    if (b == NBKT - 1 && tid == 0) A[N_NODES] = c1;

    for (int i = c0 + tid; i < c1; i += 256) {
        unsigned long long rec = R[i];
        int nl = (int)(rec & 127);
        int pos = Aex[nl] + atomicAdd(&curs[nl], 1);
        packed[pos] = (unsigned)((rec >> 8) & 0xFFFFFFu);
        normS[pos]  = (unsigned short)(rec >> 32);
    }
}

// ---------------------------------------------------------------------------
// K1 (MFMA): node tile 256/block — W swizzle amortized over 4 node-groups.
// ---------------------------------------------------------------------------
template<int IS_F32>
__device__ __forceinline__ short8 load_afrag(const void* h_raw, int row, int quad, int half)
{
    short8 r;
    if (IS_F32) {
        const float4* p = (const float4*)((const char*)h_raw + (size_t)row * 256 + half * 128 + quad * 32);
        float4 f0 = p[0], f1 = p[1];
        float fv[8] = {f0.x, f0.y, f0.z, f0.w, f1.x, f1.y, f1.z, f1.w};
#pragma unroll
        for (int j = 0; j < 8; ++j) r[j] = (short)f2bfbits(fv[j]);
    } else {
        uint4 v = *(const uint4*)((const char*)h_raw + (size_t)row * 128 + half * 64 + quad * 16);
        __builtin_memcpy(&r, &v, 16);
    }
    return r;
}

template<int IS_F32>
__device__ __forceinline__ void mfma_body(
    const void* __restrict__ h_raw,
    const void* __restrict__ w_raw,
    __hip_bfloat16* __restrict__ transformed,
    short* Wl)
{
    const int lane = threadIdx.x & 63;
    const int wave = threadIdx.x >> 6;
    const int n15  = lane & 15;
    const int quad = lane >> 4;
    const int rbase = blockIdx.y * 4;

    for (int idx = threadIdx.x; idx < 4 * 64 * 64; idx += 256) {
        int o = idx & 63, d = (idx >> 6) & 63, rl = idx >> 12;
        float wv = ldx<IS_F32>(w_raw, (size_t)((rbase + rl) * 64 + d) * 64 + o);
        int c = d >> 5, q = (d >> 3) & 3, j = d & 7;
        Wl[((rl * 2 + c) * 64 + o) * 40 + q * 8 + j] = (short)f2bfbits(wv);
    }
    __syncthreads();

    unsigned short* tb = (unsigned short*)transformed;
    const int node_blk = blockIdx.x * 256;

    for (int ng = 0; ng < 4; ++ng) {
        const int node0 = node_blk + ng * 64 + wave * 16;
        if (node0 >= N_NODES) continue;   // 50000 % 16 == 0: group fully in/out

        short8 a0 = load_afrag<IS_F32>(h_raw, node0 + n15, quad, 0);
        short8 a1 = load_afrag<IS_F32>(h_raw, node0 + n15, quad, 1);

#pragma unroll
        for (int rl = 0; rl < 4; ++rl) {
            float4v acc[4];
#pragma unroll
            for (int t = 0; t < 4; ++t) acc[t] = (float4v){0.f, 0.f, 0.f, 0.f};

#pragma unroll
            for (int t = 0; t < 4; ++t) {
                const short8* b0 = (const short8*)&Wl[((rl * 2 + 0) * 64 + t * 16 + n15) * 40 + quad * 8];
                acc[t] = __builtin_amdgcn_mfma_f32_16x16x32_bf16(a0, *b0, acc[t], 0, 0, 0);
            }
#pragma unroll
            for (int t = 0; t < 4; ++t) {
                const short8* b1 = (const short8*)&Wl[((rl * 2 + 1) * 64 + t * 16 + n15) * 40 + quad * 8];
                acc[t] = __builtin_amdgcn_mfma_f32_16x16x32_bf16(a1, *b1, acc[t], 0, 0, 0);
            }

            const int r = rbase + rl;
#pragma unroll
            for (int t = 0; t < 4; ++t) {
#pragma unroll
                for (int i = 0; i < 4; ++i) {
                    int node = node0 + quad * 4 + i;
                    tb[((size_t)node * NREL + r) * DIM + t * 16 + n15] = f2bfbits(acc[t][i]);
                }
            }
        }
    }
}

__global__ __launch_bounds__(256) void k1_mfma(
    const void* __restrict__ h_raw,
    const void* __restrict__ w_raw,
    __hip_bfloat16* __restrict__ transformed,
    const int* __restrict__ flag)
{
    __shared__ short Wl[4 * 2 * 64 * 40];   // 40 KB
    if (*flag) mfma_body<1>(h_raw, w_raw, transformed, Wl);
    else       mfma_body<0>(h_raw, w_raw, transformed, Wl);
}

// ---------------------------------------------------------------------------
// K_ACC: one wave per dst node; 4x unrolled gather loop (4 × 128 B in
// flight per wave) to hide L2/L3 latency.
// ---------------------------------------------------------------------------
template<int IS_F32>
__device__ __forceinline__ void acc_body(
    const unsigned* __restrict__ packed,
    const unsigned short* __restrict__ normS,
    const __hip_bfloat16* __restrict__ transformed,
    const int* __restrict__ A,
    void* __restrict__ out)
{
    const int lane = threadIdx.x & 63;
    const int v = blockIdx.x * 4 + (threadIdx.x >> 6);
    if (v >= N_NODES) return;

    const int start = __builtin_amdgcn_readfirstlane(A[v]);
    const int end   = __builtin_amdgcn_readfirstlane(A[v + 1]);

    const unsigned short* tb = (const unsigned short*)transformed;
    float a = 0.f;
    int i = start;
    for (; i + 4 <= end; i += 4) {
        unsigned u0 = packed[i],     u1 = packed[i + 1];
        unsigned u2 = packed[i + 2], u3 = packed[i + 3];
        float n0 = bfbits2f(normS[i]),     n1 = bfbits2f(normS[i + 1]);
        float n2 = bfbits2f(normS[i + 2]), n3 = bfbits2f(normS[i + 3]);
        unsigned off0 = ((u0 & 0xFFFFu) * NREL + (u0 >> 16)) * DIM + lane;
        unsigned off1 = ((u1 & 0xFFFFu) * NREL + (u1 >> 16)) * DIM + lane;
        unsigned off2 = ((u2 & 0xFFFFu) * NREL + (u2 >> 16)) * DIM + lane;
        unsigned off3 = ((u3 & 0xFFFFu) * NREL + (u3 >> 16)) * DIM + lane;
        float t0 = bfbits2f(tb[off0]);
        float t1 = bfbits2f(tb[off1]);
        float t2 = bfbits2f(tb[off2]);
        float t3 = bfbits2f(tb[off3]);
        a = fmaf(t0, n0, a);
        a = fmaf(t1, n1, a);
        a = fmaf(t2, n2, a);
        a = fmaf(t3, n3, a);
    }
    for (; i < end; ++i) {
        unsigned u0 = packed[i];
        float n0 = bfbits2f(normS[i]);
        unsigned off0 = ((u0 & 0xFFFFu) * NREL + (u0 >> 16)) * DIM + lane;
        a = fmaf(bfbits2f(tb[off0]), n0, a);
    }

    float r = fmaxf(a, 0.f);
    const size_t ob = (size_t)v * DIM + lane;
    if (IS_F32) {
        ((float*)out)[ob] = r;
    } else {
        ((unsigned short*)out)[ob] = f2bfbits(r);
    }
}

__global__ __launch_bounds__(256) void k_acc(
    const unsigned* __restrict__ packed,
    const unsigned short* __restrict__ normS,
    const __hip_bfloat16* __restrict__ transformed,
    const int* __restrict__ A,
    void* __restrict__ out, const int* __restrict__ flag)
{
    if (*flag) acc_body<1>(packed, normS, transformed, A, out);
    else       acc_body<0>(packed, normS, transformed, A, out);
}

// ---------------------------------------------------------------------------
extern "C" void kernel_launch(void* const* d_in, const int* in_sizes, int n_in,
                              void* d_out, int out_size, void* d_ws, size_t ws_size,
                              hipStream_t stream)
{
    const void* h      = d_in[0];
    const void* weight = d_in[1];
    const void* norm   = d_in[2];
    const int* src = (const int*)d_in[3];
    const int* dst = (const int*)d_in[4];
    const int* rel = (const int*)d_in[5];

    // ws: flag(256) | A[50001] | base[392]+tot[391] | H[782*391] | OT[391*782]
    //     | packed u32[E] | normS u16[E] | transformed bf16[N*R*64]
    //     (R u64[E] aliases transformed; consumed by k_p2 before k1_mfma)
    char* w = (char*)d_ws;
    int*   flag = (int*)w;                      w += 256;
    int*   A    = (int*)w;                      w += 200192;
    int*   base = (int*)w;                      w += 2048;
    int*   tot  = (int*)w;                      w += 2048;
    int*   H    = (int*)w;                      w += (size_t)P1_GRID * NBKT * 4;
    int*   OT   = (int*)w;                      w += (size_t)NBKT * P1_GRID * 4;
    unsigned* packed = (unsigned*)w;            w += (size_t)N_EDGES * 4;
    unsigned short* normS = (unsigned short*)w; w += (size_t)N_EDGES * 2;
    __hip_bfloat16* transformed = (__hip_bfloat16*)w;
    unsigned long long* R = (unsigned long long*)transformed;

    k_detect<<<1, 1024, 0, stream>>>((const float*)norm, flag);

    k_bhist<<<P1_GRID, 256, 0, stream>>>(dst, H);
    k_bscan1<<<NBKT, 256, 0, stream>>>(H, OT, tot);
    k_bscan2<<<1, 64, 0, stream>>>(tot, base);

    k_p1<<<P1_GRID, 256, 0, stream>>>(src, dst, rel, norm, base, OT, R, flag);
    k_p2<<<NBKT, 256, 0, stream>>>(base, R, packed, normS, A);

    dim3 g1((N_NODES + 255) / 256, 4);
    k1_mfma<<<g1, 256, 0, stream>>>(h, weight, transformed, flag);

    k_acc<<<12500, 256, 0, stream>>>(packed, normS, transformed, A, d_out, flag);
}